// Round 8
// baseline (527.505 us; speedup 1.0000x reference)
//
#include <hip/hip_runtime.h>

// GCN 2-layer forward, bucket-aggregation formulation. All fp32.
// out[d] = dinv[d] * ( sum_{e: src->d} g[src] + g[d] ) + bias,
// where g[i] = (h W)[i] * dinv[i]; self-loop is the +g[d] term.
// Edges are partitioned by dst-bucket (256 nodes/bucket) into `binned`
// (packed src<<8 | dst&255), then BOTH layers aggregate directly from the
// partition with per-bucket LDS float atomics. No CSR, no global float
// atomics, no memsets.
//   k_bhist:  per-(block,bucket) histogram, plain coalesced stores
//   k_colsum/k_scan_nb/k_rebase: parallel 2-level scan -> write bases
//   k_bin:    scatter packed edges into bucket regions (LDS cursors)
//   k_deg:    per-bucket degree count -> dinv
//   k_gemm1:  g1 = (x @ W1) * dinv
//   k_agg1:   per-bucket LDS aggregation of g1 + fused relu/W2/bias -> g2
//   k_agg2:   per-bucket LDS aggregation of g2 + bias -> out

#define BKT_SHIFT 8            // 256 nodes per bucket
#define BIN_EPT 16             // edges per thread in binning kernels (4096/block)

// Per-block bucket histogram of dst. hist[bl*NB + b] fully written.
__global__ __launch_bounds__(256) void k_bhist(
    const int* __restrict__ dst, int* __restrict__ hist, int E, int NB) {
    extern __shared__ int h[];  // NB ints
    const int t = threadIdx.x;
    const int base = blockIdx.x * (256 * BIN_EPT);
    for (int b = t; b < NB; b += 256) h[b] = 0;
    __syncthreads();
#pragma unroll
    for (int j = 0; j < BIN_EPT; ++j) {
        int e = base + j * 256 + t;
        if (e < E) atomicAdd(&h[dst[e] >> BKT_SHIFT], 1);
    }
    __syncthreads();
    for (int b = t; b < NB; b += 256)
        hist[(size_t)blockIdx.x * NB + b] = h[b];
}

// Wave per bucket: column sum of hist -> bucket_total.
__global__ __launch_bounds__(256) void k_colsum(
    const int* __restrict__ hist, int* __restrict__ bucket_total,
    int NBL, int NB) {
    const int b = blockIdx.x * 4 + (threadIdx.x >> 6);
    if (b >= NB) return;
    const int lane = threadIdx.x & 63;
    int s = 0;
    for (int bl = lane; bl < NBL; bl += 64) s += hist[(size_t)bl * NB + b];
#pragma unroll
    for (int m = 1; m < 64; m <<= 1) s += __shfl_xor(s, m);
    if (lane == 0) bucket_total[b] = s;
}

// Exclusive scan of NB (<=512) bucket totals -> bucket_base.
__global__ __launch_bounds__(512) void k_scan_nb(
    const int* __restrict__ bucket_total, int* __restrict__ bucket_base, int NB) {
    __shared__ int lds[512];
    const int t = threadIdx.x;
    int v = (t < NB) ? bucket_total[t] : 0;
    lds[t] = v;
    __syncthreads();
    for (int off = 1; off < 512; off <<= 1) {
        int u = (t >= off) ? lds[t - off] : 0;
        __syncthreads();
        lds[t] += u;
        __syncthreads();
    }
    if (t < NB) bucket_base[t] = lds[t] - v;
}

// Wave per bucket: chunked inclusive shuffle-scan down the column, rewriting
// hist[bl][b] into the exact global write base for (block bl, bucket b).
__global__ __launch_bounds__(256) void k_rebase(
    int* __restrict__ hist, const int* __restrict__ bucket_base,
    int NBL, int NB) {
    const int b = blockIdx.x * 4 + (threadIdx.x >> 6);
    if (b >= NB) return;
    const int lane = threadIdx.x & 63;
    int run = bucket_base[b];
    for (int base = 0; base < NBL; base += 64) {
        int bl = base + lane;
        int c = (bl < NBL) ? hist[(size_t)bl * NB + b] : 0;
        int inc = c;
#pragma unroll
        for (int m = 1; m < 64; m <<= 1) {
            int u = __shfl_up(inc, m);
            if (lane >= m) inc += u;
        }
        if (bl < NBL) hist[(size_t)bl * NB + b] = run + (inc - c);
        run += __shfl(inc, 63);
    }
}

// Bin packed edges (src<<8 | dst&255) into per-bucket regions of `binned`.
// LDS cursors seeded with this block's exact global bases -> no global atomics.
__global__ __launch_bounds__(256) void k_bin(
    const int* __restrict__ src, const int* __restrict__ dst,
    const int* __restrict__ hist, int* __restrict__ binned, int E, int NB) {
    extern __shared__ int lds_pos[];  // NB ints
    const int t = threadIdx.x;
    const int base = blockIdx.x * (256 * BIN_EPT);
    for (int b = t; b < NB; b += 256)
        lds_pos[b] = hist[(size_t)blockIdx.x * NB + b];
    __syncthreads();
#pragma unroll
    for (int j = 0; j < BIN_EPT; ++j) {
        int e = base + j * 256 + t;
        if (e < E) {
            int s = src[e], d = dst[e];
            int pos = atomicAdd(&lds_pos[d >> BKT_SHIFT], 1);
            binned[pos] = (s << BKT_SHIFT) | (d & 255);
        }
    }
}

// One block per bucket: degree count in LDS -> dinv.
__global__ __launch_bounds__(256) void k_deg(
    const int* __restrict__ binned, const int* __restrict__ bucket_base,
    float* __restrict__ dinv, int E, int n, int NB) {
    __shared__ int lcnt[256];
    const int b = blockIdx.x, t = threadIdx.x;
    const int lo = bucket_base[b];
    const int hi = (b + 1 < NB) ? bucket_base[b + 1] : E;
    lcnt[t] = 0;
    __syncthreads();
    for (int i = lo + t; i < hi; i += 256)
        atomicAdd(&lcnt[binned[i] & 255], 1);
    __syncthreads();
    const int node = (b << BKT_SHIFT) + t;
    if (node < n) dinv[node] = rsqrtf((float)lcnt[t] + 1.0f);
}

// g1[row][o] = (x[row] @ W1)[o] * dinv[row]
// wave-per-row: lane l covers k in {4l..4l+3} u {256+4l..256+4l+3},
// W fragment in registers, reduce-scatter via shfl_xor.
__global__ __launch_bounds__(256) void k_gemm1(
    const float* __restrict__ x, const float* __restrict__ W1,
    const float* __restrict__ dinv, float* __restrict__ g1, int n) {
    const int lane = threadIdx.x & 63;
    const int wid  = blockIdx.x * (blockDim.x >> 6) + (threadIdx.x >> 6);
    const int nw   = gridDim.x * (blockDim.x >> 6);
    const float4* __restrict__ xv = (const float4*)x;
    const float4* __restrict__ wv = (const float4*)W1;

    float wreg[8][16];
#pragma unroll
    for (int j = 0; j < 4; ++j) {
#pragma unroll
        for (int q = 0; q < 4; ++q) {
            float4 wa = wv[(4 * lane + j) * 4 + q];
            wreg[j][4 * q + 0] = wa.x; wreg[j][4 * q + 1] = wa.y;
            wreg[j][4 * q + 2] = wa.z; wreg[j][4 * q + 3] = wa.w;
            float4 wb = wv[(256 + 4 * lane + j) * 4 + q];
            wreg[4 + j][4 * q + 0] = wb.x; wreg[4 + j][4 * q + 1] = wb.y;
            wreg[4 + j][4 * q + 2] = wb.z; wreg[4 + j][4 * q + 3] = wb.w;
        }
    }

    int row = wid;
    float4 a = make_float4(0.f, 0.f, 0.f, 0.f), b = a;
    if (row < n) { a = xv[row * 128 + lane]; b = xv[row * 128 + 64 + lane]; }
    for (; row < n; row += nw) {
        int nrow = row + nw;
        float4 a2 = a, b2 = b;
        if (nrow < n) { a2 = xv[nrow * 128 + lane]; b2 = xv[nrow * 128 + 64 + lane]; }

        float av[8] = {a.x, a.y, a.z, a.w, b.x, b.y, b.z, b.w};
        float acc[16];
#pragma unroll
        for (int o = 0; o < 16; ++o) acc[o] = 0.f;
#pragma unroll
        for (int j = 0; j < 8; ++j)
#pragma unroll
            for (int o = 0; o < 16; ++o) acc[o] = fmaf(av[j], wreg[j][o], acc[o]);

#pragma unroll
        for (int i = 0; i < 8; ++i) {
            float send = (lane & 32) ? acc[i] : acc[i + 8];
            float recv = __shfl_xor(send, 32);
            float keep = (lane & 32) ? acc[i + 8] : acc[i];
            acc[i] = keep + recv;
        }
#pragma unroll
        for (int i = 0; i < 4; ++i) {
            float send = (lane & 16) ? acc[i] : acc[i + 4];
            float recv = __shfl_xor(send, 16);
            float keep = (lane & 16) ? acc[i + 4] : acc[i];
            acc[i] = keep + recv;
        }
#pragma unroll
        for (int i = 0; i < 2; ++i) {
            float send = (lane & 8) ? acc[i] : acc[i + 2];
            float recv = __shfl_xor(send, 8);
            float keep = (lane & 8) ? acc[i + 2] : acc[i];
            acc[i] = keep + recv;
        }
        {
            float send = (lane & 4) ? acc[0] : acc[1];
            float recv = __shfl_xor(send, 4);
            float keep = (lane & 4) ? acc[1] : acc[0];
            acc[0] = keep + recv;
        }
        float r = acc[0];
        r += __shfl_xor(r, 1);
        r += __shfl_xor(r, 2);
        if ((lane & 3) == 0) g1[(size_t)row * 16 + (lane >> 2)] = r * dinv[row];
        a = a2; b = b2;
    }
}

// One block per bucket (512 thr): LDS-atomic aggregation of g1 over the
// bucket's edges, then fused h2=relu(dinv*(acc+g1[d])+b1), h3=h2@W2,
// g2 = h3*dinv epilogue. acc stride 17 -> conflict-free.
__global__ __launch_bounds__(512) void k_agg1(
    const int* __restrict__ binned, const int* __restrict__ bucket_base,
    const float* __restrict__ g1, const float* __restrict__ dinv,
    const float* __restrict__ W2, const float* __restrict__ b1,
    float* __restrict__ g2, int E, int n, int NB) {
    __shared__ float acc[256 * 17];
    const int b = blockIdx.x, t = threadIdx.x;
    const int lo = bucket_base[b];
    const int hi = (b + 1 < NB) ? bucket_base[b + 1] : E;
    for (int i = t; i < 256 * 17; i += 512) acc[i] = 0.f;
    __syncthreads();
    const int f = t & 15, slot = t >> 4;  // 32 edge slots x 16 features
    for (int i = lo + slot; i < hi; i += 32) {
        int v = binned[i];
        float val = g1[(size_t)(v >> BKT_SHIFT) * 16 + f];
        atomicAdd(&acc[(v & 255) * 17 + f], val);
    }
    __syncthreads();
    if (t < 256) {
        const int node = (b << BKT_SHIFT) + t;
        if (node < n) {
            const float dv = dinv[node];
            const float4* gn = (const float4*)(g1 + (size_t)node * 16);
            float c0 = 0.f, c1 = 0.f;
#pragma unroll
            for (int q = 0; q < 4; ++q) {
                float4 g = gn[q];
                float gv[4] = {g.x, g.y, g.z, g.w};
#pragma unroll
                for (int j = 0; j < 4; ++j) {
                    int k = 4 * q + j;
                    float h2 = fmaxf(fmaf(dv, acc[t * 17 + k] + gv[j], b1[k]), 0.f);
                    c0 = fmaf(h2, W2[2 * k], c0);
                    c1 = fmaf(h2, W2[2 * k + 1], c1);
                }
            }
            ((float2*)g2)[node] = make_float2(c0 * dv, c1 * dv);
        }
    }
}

// One block per bucket (512 thr): LDS-atomic aggregation of g2 (float2),
// fused bias -> out.
__global__ __launch_bounds__(512) void k_agg2(
    const int* __restrict__ binned, const int* __restrict__ bucket_base,
    const float* __restrict__ g2, const float* __restrict__ dinv,
    const float* __restrict__ b2, float* __restrict__ out, int E, int n, int NB) {
    __shared__ float acc[512];
    const int b = blockIdx.x, t = threadIdx.x;
    const int lo = bucket_base[b];
    const int hi = (b + 1 < NB) ? bucket_base[b + 1] : E;
    acc[t] = 0.f;
    __syncthreads();
    const int c = t & 1, slot = t >> 1;  // 256 edge slots x 2 channels
    for (int i = lo + slot; i < hi; i += 256) {
        int v = binned[i];
        atomicAdd(&acc[(v & 255) * 2 + c], g2[(size_t)(v >> BKT_SHIFT) * 2 + c]);
    }
    __syncthreads();
    if (t < 256) {
        const int node = (b << BKT_SHIFT) + t;
        if (node < n) {
            const float dv = dinv[node];
            float2 g = ((const float2*)g2)[node];
            ((float2*)out)[node] = make_float2(
                fmaf(dv, acc[t * 2 + 0] + g.x, b2[0]),
                fmaf(dv, acc[t * 2 + 1] + g.y, b2[1]));
        }
    }
}

extern "C" void kernel_launch(void* const* d_in, const int* in_sizes, int n_in,
                              void* d_out, int out_size, void* d_ws, size_t ws_size,
                              hipStream_t stream) {
    const float* x  = (const float*)d_in[0];
    const int*   ei = (const int*)d_in[1];
    const float* W1 = (const float*)d_in[2];
    const float* b1 = (const float*)d_in[3];
    const float* W2 = (const float*)d_in[4];
    const float* b2 = (const float*)d_in[5];
    float* out = (float*)d_out;

    const int n = in_sizes[0] / 512;
    const int E = in_sizes[1] / 2;
    const int* src = ei;
    const int* dst = ei + E;

    const int NB = (n + (1 << BKT_SHIFT) - 1) >> BKT_SHIFT;      // buckets (<=512)
    const int nb_bin = (E + 256 * BIN_EPT - 1) / (256 * BIN_EPT); // bin blocks

    char* ws = (char*)d_ws;
    size_t off = 0;
    auto alloc = [&](size_t bytes) {
        char* p = ws + off;
        off += (bytes + 255) & ~(size_t)255;
        return p;
    };
    float* dinv      = (float*)alloc((size_t)n * 4);
    float* g1        = (float*)alloc((size_t)n * 16 * 4);
    float* g2        = (float*)alloc((size_t)n * 2 * 4);
    int*   binned    = (int*)alloc((size_t)E * 4);
    int*   hist         = (int*)alloc((size_t)nb_bin * NB * 4);
    int*   bucket_total = (int*)alloc((size_t)NB * 4);
    int*   bucket_base  = (int*)alloc((size_t)NB * 4);

    const int nb_b = (NB + 3) / 4;   // wave-per-bucket kernels, 4 waves/block

    k_bhist<<<nb_bin, 256, NB * 4, stream>>>(dst, hist, E, NB);
    k_colsum<<<nb_b, 256, 0, stream>>>(hist, bucket_total, nb_bin, NB);
    k_scan_nb<<<1, 512, 0, stream>>>(bucket_total, bucket_base, NB);
    k_rebase<<<nb_b, 256, 0, stream>>>(hist, bucket_base, nb_bin, NB);
    k_bin<<<nb_bin, 256, NB * 4, stream>>>(src, dst, hist, binned, E, NB);
    k_deg<<<NB, 256, 0, stream>>>(binned, bucket_base, dinv, E, n, NB);
    k_gemm1<<<1024, 256, 0, stream>>>(x, W1, dinv, g1, n);
    k_agg1<<<NB, 512, 0, stream>>>(binned, bucket_base, g1, dinv, W2, b1, g2, E, n, NB);
    k_agg2<<<NB, 512, 0, stream>>>(binned, bucket_base, g2, dinv, b2, out, E, n, NB);
}

// Round 9
// 247.074 us; speedup vs baseline: 2.1350x; 2.1350x over previous
//
#include <hip/hip_runtime.h>

// GCN 2-layer forward, CSR-gather formulation. All fp32.
// out[d] = dinv[d] * ( sum_{e: src->d} g[src] + g[d] ) + bias,
// where g[i] = (h W)[i] * dinv[i]; self-loop is the +g[d] term.
// CSR built via binned partition with NO global atomics and NO memsets:
//   k_bhist:  per-(block,bucket) histogram, plain coalesced stores
//   k_colsum/k_scan_nb/k_rebase: parallel 2-level scan -> write bases
//   k_bin:    scatter packed edges (src<<8|dst&255) into bucket regions
//   k_place:  per-bucket -> per-node counts/scan in LDS, emit row_start/
//             cnt/dinv and csr with LDS cursors.
//   k_gemm1:  g1 = (x @ W1) * dinv  (wave-per-row, shuffle reduce-scatter)
//   k_gather1: CSR gather of g1 (4-way MLP unroll) + fused relu/W2 -> g2
//   k_gather2: CSR gather of g2 + bias -> out

#define BKT_SHIFT 8            // 256 nodes per bucket
#define BIN_EPT 16             // edges per thread in binning kernels (4096/block)

// Per-block bucket histogram of dst. hist[bl*NB + b] fully written.
__global__ __launch_bounds__(256) void k_bhist(
    const int* __restrict__ dst, int* __restrict__ hist, int E, int NB) {
    extern __shared__ int h[];  // NB ints
    const int t = threadIdx.x;
    const int base = blockIdx.x * (256 * BIN_EPT);
    for (int b = t; b < NB; b += 256) h[b] = 0;
    __syncthreads();
#pragma unroll
    for (int j = 0; j < BIN_EPT; ++j) {
        int e = base + j * 256 + t;
        if (e < E) atomicAdd(&h[dst[e] >> BKT_SHIFT], 1);
    }
    __syncthreads();
    for (int b = t; b < NB; b += 256)
        hist[(size_t)blockIdx.x * NB + b] = h[b];
}

// Wave per bucket: column sum of hist -> bucket_total.
__global__ __launch_bounds__(256) void k_colsum(
    const int* __restrict__ hist, int* __restrict__ bucket_total,
    int NBL, int NB) {
    const int b = blockIdx.x * 4 + (threadIdx.x >> 6);
    if (b >= NB) return;
    const int lane = threadIdx.x & 63;
    int s = 0;
    for (int bl = lane; bl < NBL; bl += 64) s += hist[(size_t)bl * NB + b];
#pragma unroll
    for (int m = 1; m < 64; m <<= 1) s += __shfl_xor(s, m);
    if (lane == 0) bucket_total[b] = s;
}

// Exclusive scan of NB (<=512) bucket totals -> bucket_base.
__global__ __launch_bounds__(512) void k_scan_nb(
    const int* __restrict__ bucket_total, int* __restrict__ bucket_base, int NB) {
    __shared__ int lds[512];
    const int t = threadIdx.x;
    int v = (t < NB) ? bucket_total[t] : 0;
    lds[t] = v;
    __syncthreads();
    for (int off = 1; off < 512; off <<= 1) {
        int u = (t >= off) ? lds[t - off] : 0;
        __syncthreads();
        lds[t] += u;
        __syncthreads();
    }
    if (t < NB) bucket_base[t] = lds[t] - v;
}

// Wave per bucket: chunked inclusive shuffle-scan down the column, rewriting
// hist[bl][b] into the exact global write base for (block bl, bucket b).
__global__ __launch_bounds__(256) void k_rebase(
    int* __restrict__ hist, const int* __restrict__ bucket_base,
    int NBL, int NB) {
    const int b = blockIdx.x * 4 + (threadIdx.x >> 6);
    if (b >= NB) return;
    const int lane = threadIdx.x & 63;
    int run = bucket_base[b];
    for (int base = 0; base < NBL; base += 64) {
        int bl = base + lane;
        int c = (bl < NBL) ? hist[(size_t)bl * NB + b] : 0;
        int inc = c;
#pragma unroll
        for (int m = 1; m < 64; m <<= 1) {
            int u = __shfl_up(inc, m);
            if (lane >= m) inc += u;
        }
        if (bl < NBL) hist[(size_t)bl * NB + b] = run + (inc - c);
        run += __shfl(inc, 63);
    }
}

// Bin packed edges (src<<8 | dst&255) into per-bucket regions of `binned`.
// LDS cursors seeded with this block's exact global bases -> no global atomics.
__global__ __launch_bounds__(256) void k_bin(
    const int* __restrict__ src, const int* __restrict__ dst,
    const int* __restrict__ hist, int* __restrict__ binned, int E, int NB) {
    extern __shared__ int lds_pos[];  // NB ints
    const int t = threadIdx.x;
    const int base = blockIdx.x * (256 * BIN_EPT);
    for (int b = t; b < NB; b += 256)
        lds_pos[b] = hist[(size_t)blockIdx.x * NB + b];
    __syncthreads();
#pragma unroll
    for (int j = 0; j < BIN_EPT; ++j) {
        int e = base + j * 256 + t;
        if (e < E) {
            int s = src[e], d = dst[e];
            int pos = atomicAdd(&lds_pos[d >> BKT_SHIFT], 1);
            binned[pos] = (s << BKT_SHIFT) | (d & 255);
        }
    }
}

// One block per bucket: per-node degree count in LDS, LDS scan ->
// row_start/cnt/dinv, then place csr (src only) with LDS cursors.
__global__ __launch_bounds__(256) void k_place(
    const int* __restrict__ binned, const int* __restrict__ bucket_base,
    int* __restrict__ row_start, int* __restrict__ cnt, float* __restrict__ dinv,
    int* __restrict__ csr, int E, int n, int NB) {
    __shared__ int lcnt[256], sc[256];
    const int b = blockIdx.x;
    const int t = threadIdx.x;
    const int lo = bucket_base[b];
    const int hi = (b + 1 < NB) ? bucket_base[b + 1] : E;
    lcnt[t] = 0;
    __syncthreads();
    for (int i = lo + t; i < hi; i += 256)
        atomicAdd(&lcnt[binned[i] & 255], 1);
    __syncthreads();
    int c = lcnt[t];
    sc[t] = c;
    __syncthreads();
    for (int off = 1; off < 256; off <<= 1) {
        int u = (t >= off) ? sc[t - off] : 0;
        __syncthreads();
        sc[t] += u;
        __syncthreads();
    }
    int excl = sc[t] - c;
    const int node = (b << BKT_SHIFT) + t;
    if (node < n) {
        row_start[node] = lo + excl;
        cnt[node] = c;
        dinv[node] = rsqrtf((float)c + 1.0f);
    }
    lcnt[t] = excl;  // becomes the local cursor
    __syncthreads();
    for (int i = lo + t; i < hi; i += 256) {
        int v = binned[i];
        int r = atomicAdd(&lcnt[v & 255], 1);
        csr[lo + r] = v >> BKT_SHIFT;
    }
}

// g1[row][o] = (x[row] @ W1)[o] * dinv[row]
// wave-per-row: lane l covers k in {4l..4l+3} u {256+4l..256+4l+3},
// W fragment in registers, reduce-scatter via shfl_xor.
__global__ __launch_bounds__(256) void k_gemm1(
    const float* __restrict__ x, const float* __restrict__ W1,
    const float* __restrict__ dinv, float* __restrict__ g1, int n) {
    const int lane = threadIdx.x & 63;
    const int wid  = blockIdx.x * (blockDim.x >> 6) + (threadIdx.x >> 6);
    const int nw   = gridDim.x * (blockDim.x >> 6);
    const float4* __restrict__ xv = (const float4*)x;
    const float4* __restrict__ wv = (const float4*)W1;

    float wreg[8][16];
#pragma unroll
    for (int j = 0; j < 4; ++j) {
#pragma unroll
        for (int q = 0; q < 4; ++q) {
            float4 wa = wv[(4 * lane + j) * 4 + q];
            wreg[j][4 * q + 0] = wa.x; wreg[j][4 * q + 1] = wa.y;
            wreg[j][4 * q + 2] = wa.z; wreg[j][4 * q + 3] = wa.w;
            float4 wb = wv[(256 + 4 * lane + j) * 4 + q];
            wreg[4 + j][4 * q + 0] = wb.x; wreg[4 + j][4 * q + 1] = wb.y;
            wreg[4 + j][4 * q + 2] = wb.z; wreg[4 + j][4 * q + 3] = wb.w;
        }
    }

    int row = wid;
    float4 a = make_float4(0.f, 0.f, 0.f, 0.f), b = a;
    if (row < n) { a = xv[row * 128 + lane]; b = xv[row * 128 + 64 + lane]; }
    for (; row < n; row += nw) {
        int nrow = row + nw;
        float4 a2 = a, b2 = b;
        if (nrow < n) { a2 = xv[nrow * 128 + lane]; b2 = xv[nrow * 128 + 64 + lane]; }

        float av[8] = {a.x, a.y, a.z, a.w, b.x, b.y, b.z, b.w};
        float acc[16];
#pragma unroll
        for (int o = 0; o < 16; ++o) acc[o] = 0.f;
#pragma unroll
        for (int j = 0; j < 8; ++j)
#pragma unroll
            for (int o = 0; o < 16; ++o) acc[o] = fmaf(av[j], wreg[j][o], acc[o]);

#pragma unroll
        for (int i = 0; i < 8; ++i) {
            float send = (lane & 32) ? acc[i] : acc[i + 8];
            float recv = __shfl_xor(send, 32);
            float keep = (lane & 32) ? acc[i + 8] : acc[i];
            acc[i] = keep + recv;
        }
#pragma unroll
        for (int i = 0; i < 4; ++i) {
            float send = (lane & 16) ? acc[i] : acc[i + 4];
            float recv = __shfl_xor(send, 16);
            float keep = (lane & 16) ? acc[i + 4] : acc[i];
            acc[i] = keep + recv;
        }
#pragma unroll
        for (int i = 0; i < 2; ++i) {
            float send = (lane & 8) ? acc[i] : acc[i + 2];
            float recv = __shfl_xor(send, 8);
            float keep = (lane & 8) ? acc[i + 2] : acc[i];
            acc[i] = keep + recv;
        }
        {
            float send = (lane & 4) ? acc[0] : acc[1];
            float recv = __shfl_xor(send, 4);
            float keep = (lane & 4) ? acc[1] : acc[0];
            acc[0] = keep + recv;
        }
        float r = acc[0];
        r += __shfl_xor(r, 1);
        r += __shfl_xor(r, 2);
        if ((lane & 3) == 0) g1[(size_t)row * 16 + (lane >> 2)] = r * dinv[row];
        a = a2; b = b2;
    }
}

// Wave per node: gather-sum g1 over CSR neighbors (4-way MLP unroll), fuse
// h2=relu(...), h3=h2@W2, g2=h3*dinv.
// Lane layout: lane = eo*16 + f (4 edge slots x 16 features).
__global__ __launch_bounds__(256) void k_gather1(
    const int* __restrict__ row_start, const int* __restrict__ cnt,
    const int* __restrict__ csr, const float* __restrict__ g1,
    const float* __restrict__ dinv, const float* __restrict__ W2,
    const float* __restrict__ b1, float* __restrict__ g2, int n) {
    const int wid = blockIdx.x * 4 + (threadIdx.x >> 6);
    if (wid >= n) return;
    const int lane = threadIdx.x & 63;
    const int f = lane & 15, eo = lane >> 4;
    const int base = row_start[wid], deg = cnt[wid];
    float acc = 0.f;
    int j = eo;
    // 4-way: 4 independent csr+gather chains in flight per lane.
    for (; j + 12 < deg; j += 16) {
        int s0 = csr[base + j];
        int s1 = csr[base + j + 4];
        int s2 = csr[base + j + 8];
        int s3 = csr[base + j + 12];
        float v0 = g1[(size_t)s0 * 16 + f];
        float v1 = g1[(size_t)s1 * 16 + f];
        float v2 = g1[(size_t)s2 * 16 + f];
        float v3 = g1[(size_t)s3 * 16 + f];
        acc += (v0 + v1) + (v2 + v3);
    }
    for (; j < deg; j += 4) {
        int s = csr[base + j];
        acc += g1[(size_t)s * 16 + f];
    }
    acc += __shfl_xor(acc, 16);
    acc += __shfl_xor(acc, 32);
    const float dv = dinv[wid];
    float h2 = fmaxf(fmaf(dv, acc + g1[(size_t)wid * 16 + f], b1[f]), 0.f);
    float p0 = h2 * W2[2 * f], p1 = h2 * W2[2 * f + 1];
#pragma unroll
    for (int m = 1; m < 16; m <<= 1) {
        p0 += __shfl_xor(p0, m);
        p1 += __shfl_xor(p1, m);
    }
    if (lane == 0) ((float2*)g2)[wid] = make_float2(p0 * dv, p1 * dv);
}

// Wave per node: gather-sum float2 g2 over CSR neighbors, fuse bias -> out.
__global__ __launch_bounds__(256) void k_gather2(
    const int* __restrict__ row_start, const int* __restrict__ cnt,
    const int* __restrict__ csr, const float* __restrict__ g2,
    const float* __restrict__ dinv, const float* __restrict__ b2,
    float* __restrict__ out, int n) {
    const int wid = blockIdx.x * 4 + (threadIdx.x >> 6);
    if (wid >= n) return;
    const int lane = threadIdx.x & 63;
    const int base = row_start[wid], deg = cnt[wid];
    float a0 = 0.f, a1 = 0.f;
    for (int j = lane; j < deg; j += 64) {
        int s = csr[base + j];
        float2 v = ((const float2*)g2)[s];
        a0 += v.x; a1 += v.y;
    }
#pragma unroll
    for (int m = 1; m < 64; m <<= 1) {
        a0 += __shfl_xor(a0, m);
        a1 += __shfl_xor(a1, m);
    }
    if (lane == 0) {
        float dv = dinv[wid];
        float2 g = ((const float2*)g2)[wid];
        ((float2*)out)[wid] = make_float2(fmaf(dv, a0 + g.x, b2[0]),
                                          fmaf(dv, a1 + g.y, b2[1]));
    }
}

extern "C" void kernel_launch(void* const* d_in, const int* in_sizes, int n_in,
                              void* d_out, int out_size, void* d_ws, size_t ws_size,
                              hipStream_t stream) {
    const float* x  = (const float*)d_in[0];
    const int*   ei = (const int*)d_in[1];
    const float* W1 = (const float*)d_in[2];
    const float* b1 = (const float*)d_in[3];
    const float* W2 = (const float*)d_in[4];
    const float* b2 = (const float*)d_in[5];
    float* out = (float*)d_out;

    const int n = in_sizes[0] / 512;
    const int E = in_sizes[1] / 2;
    const int* src = ei;
    const int* dst = ei + E;

    const int NB = (n + (1 << BKT_SHIFT) - 1) >> BKT_SHIFT;      // buckets (<=512)
    const int nb_bin = (E + 256 * BIN_EPT - 1) / (256 * BIN_EPT); // bin blocks

    char* ws = (char*)d_ws;
    size_t off = 0;
    auto alloc = [&](size_t bytes) {
        char* p = ws + off;
        off += (bytes + 255) & ~(size_t)255;
        return p;
    };
    float* dinv      = (float*)alloc((size_t)n * 4);
    float* g1        = (float*)alloc((size_t)n * 16 * 4);
    float* g2        = (float*)alloc((size_t)n * 2 * 4);
    int*   cnt       = (int*)alloc((size_t)n * 4);
    int*   row_start = (int*)alloc((size_t)n * 4);
    int*   csr       = (int*)alloc((size_t)E * 4);
    int*   binned    = (int*)alloc((size_t)E * 4);
    int*   hist         = (int*)alloc((size_t)nb_bin * NB * 4);
    int*   bucket_total = (int*)alloc((size_t)NB * 4);
    int*   bucket_base  = (int*)alloc((size_t)NB * 4);

    const int nb_w = (n + 3) / 4;    // wave-per-node kernels, 4 waves/block
    const int nb_b = (NB + 3) / 4;   // wave-per-bucket kernels, 4 waves/block

    k_bhist<<<nb_bin, 256, NB * 4, stream>>>(dst, hist, E, NB);
    k_colsum<<<nb_b, 256, 0, stream>>>(hist, bucket_total, nb_bin, NB);
    k_scan_nb<<<1, 512, 0, stream>>>(bucket_total, bucket_base, NB);
    k_rebase<<<nb_b, 256, 0, stream>>>(hist, bucket_base, nb_bin, NB);
    k_bin<<<nb_bin, 256, NB * 4, stream>>>(src, dst, hist, binned, E, NB);
    k_place<<<NB, 256, 0, stream>>>(binned, bucket_base, row_start, cnt, dinv, csr, E, n, NB);
    k_gemm1<<<1024, 256, 0, stream>>>(x, W1, dinv, g1, n);
    k_gather1<<<nb_w, 256, 0, stream>>>(row_start, cnt, csr, g1, dinv, W2, b1, g2, n);
    k_gather2<<<nb_w, 256, 0, stream>>>(row_start, cnt, csr, g2, dinv, b2, out, n);
}

// Round 10
// 246.017 us; speedup vs baseline: 2.1442x; 1.0043x over previous
//
#include <hip/hip_runtime.h>

// GCN 2-layer forward, CSR-gather formulation. All fp32.
// out[d] = dinv[d] * ( sum_{e: src->d} g[src] + g[d] ) + bias,
// where g[i] = (h W)[i] * dinv[i]; self-loop is the +g[d] term.
// CSR built via binned partition (atomic-reserve variant):
//   k_bhist:  LDS bucket histogram -> global atomicAdd bucket totals
//   k_scan_nb: scan totals -> bucket_base; seed bucket_cursor = base
//   k_bin:    stage edges in regs, LDS count, one global reserve per
//             (block,bucket), scatter packed (src<<8|dst&255) into regions
//   k_place:  per-bucket (512 thr, 4x staged): per-node counts/scan in LDS,
//             emit row_start (with sentinel row_start[n]=E) + dinv, place csr.
//   k_gemm1:  g1 = (x @ W1) * dinv  (wave-per-row, shuffle reduce-scatter)
//   k_gather1: CSR gather of g1 (4-way MLP unroll) + fused relu/W2 -> g2
//   k_gather2: CSR gather of g2 + bias -> out
// deg is implicit: row_start[i+1] - row_start[i].

#define BKT_SHIFT 8            // 256 nodes per bucket
#define BIN_EPT 16             // edges per thread in binning kernels (4096/block)

// LDS bucket histogram of dst -> global atomic bucket totals.
__global__ __launch_bounds__(256) void k_bhist(
    const int* __restrict__ dst, int* __restrict__ bucket_cnt, int E, int NB) {
    extern __shared__ int h[];  // NB ints
    const int t = threadIdx.x;
    const int base = blockIdx.x * (256 * BIN_EPT);
    for (int b = t; b < NB; b += 256) h[b] = 0;
    __syncthreads();
#pragma unroll
    for (int j = 0; j < BIN_EPT; ++j) {
        int e = base + j * 256 + t;
        if (e < E) atomicAdd(&h[dst[e] >> BKT_SHIFT], 1);
    }
    __syncthreads();
    for (int b = t; b < NB; b += 256) {
        int c = h[b];
        if (c > 0) atomicAdd(&bucket_cnt[b], c);
    }
}

// Exclusive scan of NB (<=512) bucket totals -> bucket_base; seed cursor.
__global__ __launch_bounds__(512) void k_scan_nb(
    const int* __restrict__ bucket_cnt, int* __restrict__ bucket_base,
    int* __restrict__ bucket_cursor, int NB) {
    __shared__ int lds[512];
    const int t = threadIdx.x;
    int v = (t < NB) ? bucket_cnt[t] : 0;
    lds[t] = v;
    __syncthreads();
    for (int off = 1; off < 512; off <<= 1) {
        int u = (t >= off) ? lds[t - off] : 0;
        __syncthreads();
        lds[t] += u;
        __syncthreads();
    }
    if (t < NB) {
        int base = lds[t] - v;
        bucket_base[t] = base;
        bucket_cursor[t] = base;
    }
}

// Bin packed edges (src<<8 | dst&255) into per-bucket regions of `binned`.
// Register-staged edges; LDS count; one global reserve per (block,bucket).
__global__ __launch_bounds__(256) void k_bin(
    const int* __restrict__ src, const int* __restrict__ dst,
    int* __restrict__ bucket_cursor, int* __restrict__ binned, int E, int NB) {
    extern __shared__ int lds_pos[];  // NB ints
    const int t = threadIdx.x;
    const int base = blockIdx.x * (256 * BIN_EPT);
    for (int b = t; b < NB; b += 256) lds_pos[b] = 0;
    __syncthreads();
    int s_[BIN_EPT], d_[BIN_EPT];
#pragma unroll
    for (int j = 0; j < BIN_EPT; ++j) {
        int e = base + j * 256 + t;
        if (e < E) {
            s_[j] = src[e];
            d_[j] = dst[e];
            atomicAdd(&lds_pos[d_[j] >> BKT_SHIFT], 1);
        }
    }
    __syncthreads();
    for (int b = t; b < NB; b += 256) {
        int c = lds_pos[b];
        int g = (c > 0) ? atomicAdd(&bucket_cursor[b], c) : 0;
        lds_pos[b] = g;  // absolute write base (cursor seeded with bucket_base)
    }
    __syncthreads();
#pragma unroll
    for (int j = 0; j < BIN_EPT; ++j) {
        int e = base + j * 256 + t;
        if (e < E) {
            int pos = atomicAdd(&lds_pos[d_[j] >> BKT_SHIFT], 1);
            binned[pos] = (s_[j] << BKT_SHIFT) | (d_[j] & 255);
        }
    }
}

// One block (512 thr) per bucket: per-node degree count in LDS (4x staged),
// LDS scan -> row_start (sentinel row_start[n]=E) + dinv, place csr.
__global__ __launch_bounds__(512) void k_place(
    const int* __restrict__ binned, const int* __restrict__ bucket_base,
    int* __restrict__ row_start, float* __restrict__ dinv,
    int* __restrict__ csr, int E, int n, int NB) {
    __shared__ int lcnt[256], sc[256];
    const int b = blockIdx.x;
    const int t = threadIdx.x;
    const int lo = bucket_base[b];
    const int hi = (b + 1 < NB) ? bucket_base[b + 1] : E;
    if (t < 256) lcnt[t] = 0;
    __syncthreads();
    int i = lo + t;
    for (; i + 3 * 512 < hi; i += 4 * 512) {
        int v0 = binned[i], v1 = binned[i + 512];
        int v2 = binned[i + 1024], v3 = binned[i + 1536];
        atomicAdd(&lcnt[v0 & 255], 1);
        atomicAdd(&lcnt[v1 & 255], 1);
        atomicAdd(&lcnt[v2 & 255], 1);
        atomicAdd(&lcnt[v3 & 255], 1);
    }
    for (; i < hi; i += 512) atomicAdd(&lcnt[binned[i] & 255], 1);
    __syncthreads();
    int c = 0;
    if (t < 256) { c = lcnt[t]; sc[t] = c; }
    __syncthreads();
    for (int off = 1; off < 256; off <<= 1) {
        int u = 0;
        if (t < 256 && t >= off) u = sc[t - off];
        __syncthreads();
        if (t < 256) sc[t] += u;
        __syncthreads();
    }
    if (t < 256) {
        int excl = sc[t] - c;
        const int node = (b << BKT_SHIFT) + t;
        if (node <= n) {
            row_start[node] = lo + excl;  // node==n -> hi==E sentinel
            if (node < n) dinv[node] = rsqrtf((float)c + 1.0f);
        }
        lcnt[t] = excl;  // becomes the local cursor
    }
    __syncthreads();
    i = lo + t;
    for (; i + 3 * 512 < hi; i += 4 * 512) {
        int v0 = binned[i], v1 = binned[i + 512];
        int v2 = binned[i + 1024], v3 = binned[i + 1536];
        int r0 = atomicAdd(&lcnt[v0 & 255], 1); csr[lo + r0] = v0 >> BKT_SHIFT;
        int r1 = atomicAdd(&lcnt[v1 & 255], 1); csr[lo + r1] = v1 >> BKT_SHIFT;
        int r2 = atomicAdd(&lcnt[v2 & 255], 1); csr[lo + r2] = v2 >> BKT_SHIFT;
        int r3 = atomicAdd(&lcnt[v3 & 255], 1); csr[lo + r3] = v3 >> BKT_SHIFT;
    }
    for (; i < hi; i += 512) {
        int v = binned[i];
        int r = atomicAdd(&lcnt[v & 255], 1);
        csr[lo + r] = v >> BKT_SHIFT;
    }
}

// g1[row][o] = (x[row] @ W1)[o] * dinv[row]
// wave-per-row: lane l covers k in {4l..4l+3} u {256+4l..256+4l+3},
// W fragment in registers, reduce-scatter via shfl_xor.
__global__ __launch_bounds__(256) void k_gemm1(
    const float* __restrict__ x, const float* __restrict__ W1,
    const float* __restrict__ dinv, float* __restrict__ g1, int n) {
    const int lane = threadIdx.x & 63;
    const int wid  = blockIdx.x * (blockDim.x >> 6) + (threadIdx.x >> 6);
    const int nw   = gridDim.x * (blockDim.x >> 6);
    const float4* __restrict__ xv = (const float4*)x;
    const float4* __restrict__ wv = (const float4*)W1;

    float wreg[8][16];
#pragma unroll
    for (int j = 0; j < 4; ++j) {
#pragma unroll
        for (int q = 0; q < 4; ++q) {
            float4 wa = wv[(4 * lane + j) * 4 + q];
            wreg[j][4 * q + 0] = wa.x; wreg[j][4 * q + 1] = wa.y;
            wreg[j][4 * q + 2] = wa.z; wreg[j][4 * q + 3] = wa.w;
            float4 wb = wv[(256 + 4 * lane + j) * 4 + q];
            wreg[4 + j][4 * q + 0] = wb.x; wreg[4 + j][4 * q + 1] = wb.y;
            wreg[4 + j][4 * q + 2] = wb.z; wreg[4 + j][4 * q + 3] = wb.w;
        }
    }

    int row = wid;
    float4 a = make_float4(0.f, 0.f, 0.f, 0.f), b = a;
    if (row < n) { a = xv[row * 128 + lane]; b = xv[row * 128 + 64 + lane]; }
    for (; row < n; row += nw) {
        int nrow = row + nw;
        float4 a2 = a, b2 = b;
        if (nrow < n) { a2 = xv[nrow * 128 + lane]; b2 = xv[nrow * 128 + 64 + lane]; }

        float av[8] = {a.x, a.y, a.z, a.w, b.x, b.y, b.z, b.w};
        float acc[16];
#pragma unroll
        for (int o = 0; o < 16; ++o) acc[o] = 0.f;
#pragma unroll
        for (int j = 0; j < 8; ++j)
#pragma unroll
            for (int o = 0; o < 16; ++o) acc[o] = fmaf(av[j], wreg[j][o], acc[o]);

#pragma unroll
        for (int i = 0; i < 8; ++i) {
            float send = (lane & 32) ? acc[i] : acc[i + 8];
            float recv = __shfl_xor(send, 32);
            float keep = (lane & 32) ? acc[i + 8] : acc[i];
            acc[i] = keep + recv;
        }
#pragma unroll
        for (int i = 0; i < 4; ++i) {
            float send = (lane & 16) ? acc[i] : acc[i + 4];
            float recv = __shfl_xor(send, 16);
            float keep = (lane & 16) ? acc[i + 4] : acc[i];
            acc[i] = keep + recv;
        }
#pragma unroll
        for (int i = 0; i < 2; ++i) {
            float send = (lane & 8) ? acc[i] : acc[i + 2];
            float recv = __shfl_xor(send, 8);
            float keep = (lane & 8) ? acc[i + 2] : acc[i];
            acc[i] = keep + recv;
        }
        {
            float send = (lane & 4) ? acc[0] : acc[1];
            float recv = __shfl_xor(send, 4);
            float keep = (lane & 4) ? acc[1] : acc[0];
            acc[0] = keep + recv;
        }
        float r = acc[0];
        r += __shfl_xor(r, 1);
        r += __shfl_xor(r, 2);
        if ((lane & 3) == 0) g1[(size_t)row * 16 + (lane >> 2)] = r * dinv[row];
        a = a2; b = b2;
    }
}

// Wave per node: gather-sum g1 over CSR neighbors (4-way MLP unroll), fuse
// h2=relu(...), h3=h2@W2, g2=h3*dinv.
// Lane layout: lane = eo*16 + f (4 edge slots x 16 features).
__global__ __launch_bounds__(256) void k_gather1(
    const int* __restrict__ row_start, const int* __restrict__ csr,
    const float* __restrict__ g1, const float* __restrict__ dinv,
    const float* __restrict__ W2, const float* __restrict__ b1,
    float* __restrict__ g2, int n) {
    const int wid = blockIdx.x * 4 + (threadIdx.x >> 6);
    if (wid >= n) return;
    const int lane = threadIdx.x & 63;
    const int f = lane & 15, eo = lane >> 4;
    const int base = row_start[wid];
    const int deg = row_start[wid + 1] - base;
    float acc = 0.f;
    int j = eo;
    // 4-way: 4 independent csr+gather chains in flight per lane.
    for (; j + 12 < deg; j += 16) {
        int s0 = csr[base + j];
        int s1 = csr[base + j + 4];
        int s2 = csr[base + j + 8];
        int s3 = csr[base + j + 12];
        float v0 = g1[(size_t)s0 * 16 + f];
        float v1 = g1[(size_t)s1 * 16 + f];
        float v2 = g1[(size_t)s2 * 16 + f];
        float v3 = g1[(size_t)s3 * 16 + f];
        acc += (v0 + v1) + (v2 + v3);
    }
    for (; j < deg; j += 4) {
        int s = csr[base + j];
        acc += g1[(size_t)s * 16 + f];
    }
    acc += __shfl_xor(acc, 16);
    acc += __shfl_xor(acc, 32);
    const float dv = dinv[wid];
    float h2 = fmaxf(fmaf(dv, acc + g1[(size_t)wid * 16 + f], b1[f]), 0.f);
    float p0 = h2 * W2[2 * f], p1 = h2 * W2[2 * f + 1];
#pragma unroll
    for (int m = 1; m < 16; m <<= 1) {
        p0 += __shfl_xor(p0, m);
        p1 += __shfl_xor(p1, m);
    }
    if (lane == 0) ((float2*)g2)[wid] = make_float2(p0 * dv, p1 * dv);
}

// Wave per node: gather-sum float2 g2 over CSR neighbors, fuse bias -> out.
__global__ __launch_bounds__(256) void k_gather2(
    const int* __restrict__ row_start, const int* __restrict__ csr,
    const float* __restrict__ g2, const float* __restrict__ dinv,
    const float* __restrict__ b2, float* __restrict__ out, int n) {
    const int wid = blockIdx.x * 4 + (threadIdx.x >> 6);
    if (wid >= n) return;
    const int lane = threadIdx.x & 63;
    const int base = row_start[wid];
    const int deg = row_start[wid + 1] - base;
    float a0 = 0.f, a1 = 0.f;
    for (int j = lane; j < deg; j += 64) {
        int s = csr[base + j];
        float2 v = ((const float2*)g2)[s];
        a0 += v.x; a1 += v.y;
    }
#pragma unroll
    for (int m = 1; m < 64; m <<= 1) {
        a0 += __shfl_xor(a0, m);
        a1 += __shfl_xor(a1, m);
    }
    if (lane == 0) {
        float dv = dinv[wid];
        float2 g = ((const float2*)g2)[wid];
        ((float2*)out)[wid] = make_float2(fmaf(dv, a0 + g.x, b2[0]),
                                          fmaf(dv, a1 + g.y, b2[1]));
    }
}

extern "C" void kernel_launch(void* const* d_in, const int* in_sizes, int n_in,
                              void* d_out, int out_size, void* d_ws, size_t ws_size,
                              hipStream_t stream) {
    const float* x  = (const float*)d_in[0];
    const int*   ei = (const int*)d_in[1];
    const float* W1 = (const float*)d_in[2];
    const float* b1 = (const float*)d_in[3];
    const float* W2 = (const float*)d_in[4];
    const float* b2 = (const float*)d_in[5];
    float* out = (float*)d_out;

    const int n = in_sizes[0] / 512;
    const int E = in_sizes[1] / 2;
    const int* src = ei;
    const int* dst = ei + E;

    const int NB = (n + (1 << BKT_SHIFT) - 1) >> BKT_SHIFT;      // buckets (<=512)
    const int nb_bin = (E + 256 * BIN_EPT - 1) / (256 * BIN_EPT); // bin blocks

    char* ws = (char*)d_ws;
    size_t off = 0;
    auto alloc = [&](size_t bytes) {
        char* p = ws + off;
        off += (bytes + 255) & ~(size_t)255;
        return p;
    };
    float* dinv      = (float*)alloc((size_t)n * 4);
    float* g1        = (float*)alloc((size_t)n * 16 * 4);
    float* g2        = (float*)alloc((size_t)n * 2 * 4);
    int*   row_start = (int*)alloc(((size_t)n + 1) * 4);  // +1 sentinel
    int*   csr       = (int*)alloc((size_t)E * 4);
    int*   binned    = (int*)alloc((size_t)E * 4);
    int*   bucket_cnt    = (int*)alloc((size_t)NB * 4);
    int*   bucket_base   = (int*)alloc((size_t)NB * 4);
    int*   bucket_cursor = (int*)alloc((size_t)NB * 4);

    hipMemsetAsync(bucket_cnt, 0, (size_t)NB * 4, stream);

    const int nb_w = (n + 3) / 4;    // wave-per-node kernels, 4 waves/block

    k_bhist<<<nb_bin, 256, NB * 4, stream>>>(dst, bucket_cnt, E, NB);
    k_scan_nb<<<1, 512, 0, stream>>>(bucket_cnt, bucket_base, bucket_cursor, NB);
    k_bin<<<nb_bin, 256, NB * 4, stream>>>(src, dst, bucket_cursor, binned, E, NB);
    k_place<<<NB, 512, 0, stream>>>(binned, bucket_base, row_start, dinv, csr, E, n, NB);
    k_gemm1<<<1024, 256, 0, stream>>>(x, W1, dinv, g1, n);
    k_gather1<<<nb_w, 256, 0, stream>>>(row_start, csr, g1, dinv, W2, b1, g2, n);
    k_gather2<<<nb_w, 256, 0, stream>>>(row_start, csr, g2, dinv, b2, out, n);
}

// Round 11
// 245.772 us; speedup vs baseline: 2.1463x; 1.0010x over previous
//
#include <hip/hip_runtime.h>

// GCN 2-layer forward, CSR-gather formulation. All fp32.
// out[d] = dinv[d] * ( sum_{e: src->d} g[src] + g[d] ) + bias,
// where g[i] = (h W)[i] * dinv[i]; self-loop is the +g[d] term.
// CSR built via binned partition (atomic-reserve + LDS counting sort):
//   k_bhist:  LDS bucket histogram -> global atomicAdd bucket totals
//   k_scan_nb: scan totals -> bucket_base; seed bucket_cursor = base
//   k_bin:    stage edges in regs, LDS hist+scan, one global reserve per
//             (block,bucket), LDS counting sort, COALESCED write of packed
//             (src<<8|dst&255) runs into bucket regions
//   k_place:  per-bucket (512 thr): per-node counts/scan in LDS, emit
//             row_start (sentinel row_start[n]=E) + dinv, place csr.
//   k_gemm1:  g1 = (x @ W1) * dinv  (wave-per-row, shuffle reduce-scatter)
//   k_gather1: CSR gather of g1 (4-way MLP unroll) + fused relu/W2 -> g2
//   k_gather2: CSR gather of g2 + bias -> out
// deg is implicit: row_start[i+1] - row_start[i].

#define BKT_SHIFT 8            // 256 nodes per bucket
#define BIN_EPT 16             // edges per thread in binning kernels (4096/block)

// LDS bucket histogram of dst -> global atomic bucket totals.
__global__ __launch_bounds__(256) void k_bhist(
    const int* __restrict__ dst, int* __restrict__ bucket_cnt, int E, int NB) {
    extern __shared__ int h[];  // NB ints
    const int t = threadIdx.x;
    const int base = blockIdx.x * (256 * BIN_EPT);
    for (int b = t; b < NB; b += 256) h[b] = 0;
    __syncthreads();
#pragma unroll
    for (int j = 0; j < BIN_EPT; ++j) {
        int e = base + j * 256 + t;
        if (e < E) atomicAdd(&h[dst[e] >> BKT_SHIFT], 1);
    }
    __syncthreads();
    for (int b = t; b < NB; b += 256) {
        int c = h[b];
        if (c > 0) atomicAdd(&bucket_cnt[b], c);
    }
}

// Exclusive scan of NB (<=512) bucket totals -> bucket_base; seed cursor.
__global__ __launch_bounds__(512) void k_scan_nb(
    const int* __restrict__ bucket_cnt, int* __restrict__ bucket_base,
    int* __restrict__ bucket_cursor, int NB) {
    __shared__ int lds[512];
    const int t = threadIdx.x;
    int v = (t < NB) ? bucket_cnt[t] : 0;
    lds[t] = v;
    __syncthreads();
    for (int off = 1; off < 512; off <<= 1) {
        int u = (t >= off) ? lds[t - off] : 0;
        __syncthreads();
        lds[t] += u;
        __syncthreads();
    }
    if (t < NB) {
        int base = lds[t] - v;
        bucket_base[t] = base;
        bucket_cursor[t] = base;
    }
}

// Bin packed edges (src<<8 | dst&255) into per-bucket regions of `binned`.
// LDS counting sort inside the block -> coalesced run writes.
// Dynamic LDS layout: h[NB] (hist->cursor), ls[NB] (local excl start),
// gb[NB] (global base), sorted[4096] int, bkt[4096] ushort.
__global__ __launch_bounds__(256) void k_bin(
    const int* __restrict__ src, const int* __restrict__ dst,
    int* __restrict__ bucket_cursor, int* __restrict__ binned, int E, int NB) {
    extern __shared__ int lds[];
    int* h  = lds;
    int* ls = lds + NB;
    int* gb = lds + 2 * NB;
    int* sorted = lds + 3 * NB;
    unsigned short* bkt = (unsigned short*)(sorted + 256 * BIN_EPT);
    const int t = threadIdx.x;
    const int base = blockIdx.x * (256 * BIN_EPT);
    const int count = min(256 * BIN_EPT, E - base);  // valid edges this block

    for (int b = t; b < NB; b += 256) h[b] = 0;
    __syncthreads();
    // Stage edges in registers + local histogram.
    int s_[BIN_EPT], d_[BIN_EPT];
#pragma unroll
    for (int j = 0; j < BIN_EPT; ++j) {
        int e = base + j * 256 + t;
        if (e < E) {
            s_[j] = src[e];
            d_[j] = dst[e];
            atomicAdd(&h[d_[j] >> BKT_SHIFT], 1);
        }
    }
    __syncthreads();
    // Inclusive Hillis-Steele scan of h into ls (512 padded slots, 2/thread).
    {
        int i0 = t, i1 = t + 256;
        ls[i0] = (i0 < NB) ? h[i0] : 0;
        ls[i1] = (i1 < NB) ? h[i1] : 0;
        __syncthreads();
        for (int off = 1; off < 512; off <<= 1) {
            int a0 = (i0 >= off) ? ls[i0 - off] : 0;
            int a1 = (i1 >= off) ? ls[i1 - off] : 0;
            __syncthreads();
            ls[i0] += a0; ls[i1] += a1;
            __syncthreads();
        }
    }
    // ls -> exclusive; reserve global space; h becomes local sort cursor.
    for (int b = t; b < NB; b += 256) {
        int c = h[b];
        int ex = ls[b] - c;
        ls[b] = ex;
        gb[b] = (c > 0) ? atomicAdd(&bucket_cursor[b], c) : 0;
        h[b] = ex;
    }
    __syncthreads();
    // Counting sort into LDS.
#pragma unroll
    for (int j = 0; j < BIN_EPT; ++j) {
        int e = base + j * 256 + t;
        if (e < E) {
            int b = d_[j] >> BKT_SHIFT;
            int r = atomicAdd(&h[b], 1);
            sorted[r] = (s_[j] << BKT_SHIFT) | (d_[j] & 255);
            bkt[r] = (unsigned short)b;
        }
    }
    __syncthreads();
    // Coalesced write-out: consecutive slots -> consecutive positions in the
    // same bucket's reserved region.
#pragma unroll
    for (int j = 0; j < BIN_EPT; ++j) {
        int i = j * 256 + t;
        if (i < count) {
            int b = bkt[i];
            binned[gb[b] + (i - ls[b])] = sorted[i];
        }
    }
}

// One block (512 thr) per bucket: per-node degree count in LDS (4x staged),
// LDS scan -> row_start (sentinel row_start[n]=E) + dinv, place csr.
__global__ __launch_bounds__(512) void k_place(
    const int* __restrict__ binned, const int* __restrict__ bucket_base,
    int* __restrict__ row_start, float* __restrict__ dinv,
    int* __restrict__ csr, int E, int n, int NB) {
    __shared__ int lcnt[256], sc[256];
    const int b = blockIdx.x;
    const int t = threadIdx.x;
    const int lo = bucket_base[b];
    const int hi = (b + 1 < NB) ? bucket_base[b + 1] : E;
    if (t < 256) lcnt[t] = 0;
    __syncthreads();
    int i = lo + t;
    for (; i + 3 * 512 < hi; i += 4 * 512) {
        int v0 = binned[i], v1 = binned[i + 512];
        int v2 = binned[i + 1024], v3 = binned[i + 1536];
        atomicAdd(&lcnt[v0 & 255], 1);
        atomicAdd(&lcnt[v1 & 255], 1);
        atomicAdd(&lcnt[v2 & 255], 1);
        atomicAdd(&lcnt[v3 & 255], 1);
    }
    for (; i < hi; i += 512) atomicAdd(&lcnt[binned[i] & 255], 1);
    __syncthreads();
    int c = 0;
    if (t < 256) { c = lcnt[t]; sc[t] = c; }
    __syncthreads();
    for (int off = 1; off < 256; off <<= 1) {
        int u = 0;
        if (t < 256 && t >= off) u = sc[t - off];
        __syncthreads();
        if (t < 256) sc[t] += u;
        __syncthreads();
    }
    if (t < 256) {
        int excl = sc[t] - c;
        const int node = (b << BKT_SHIFT) + t;
        if (node <= n) {
            row_start[node] = lo + excl;  // node==n -> hi==E sentinel
            if (node < n) dinv[node] = rsqrtf((float)c + 1.0f);
        }
        lcnt[t] = excl;  // becomes the local cursor
    }
    __syncthreads();
    i = lo + t;
    for (; i + 3 * 512 < hi; i += 4 * 512) {
        int v0 = binned[i], v1 = binned[i + 512];
        int v2 = binned[i + 1024], v3 = binned[i + 1536];
        int r0 = atomicAdd(&lcnt[v0 & 255], 1); csr[lo + r0] = v0 >> BKT_SHIFT;
        int r1 = atomicAdd(&lcnt[v1 & 255], 1); csr[lo + r1] = v1 >> BKT_SHIFT;
        int r2 = atomicAdd(&lcnt[v2 & 255], 1); csr[lo + r2] = v2 >> BKT_SHIFT;
        int r3 = atomicAdd(&lcnt[v3 & 255], 1); csr[lo + r3] = v3 >> BKT_SHIFT;
    }
    for (; i < hi; i += 512) {
        int v = binned[i];
        int r = atomicAdd(&lcnt[v & 255], 1);
        csr[lo + r] = v >> BKT_SHIFT;
    }
}

// g1[row][o] = (x[row] @ W1)[o] * dinv[row]
// wave-per-row: lane l covers k in {4l..4l+3} u {256+4l..256+4l+3},
// W fragment in registers, reduce-scatter via shfl_xor.
__global__ __launch_bounds__(256) void k_gemm1(
    const float* __restrict__ x, const float* __restrict__ W1,
    const float* __restrict__ dinv, float* __restrict__ g1, int n) {
    const int lane = threadIdx.x & 63;
    const int wid  = blockIdx.x * (blockDim.x >> 6) + (threadIdx.x >> 6);
    const int nw   = gridDim.x * (blockDim.x >> 6);
    const float4* __restrict__ xv = (const float4*)x;
    const float4* __restrict__ wv = (const float4*)W1;

    float wreg[8][16];
#pragma unroll
    for (int j = 0; j < 4; ++j) {
#pragma unroll
        for (int q = 0; q < 4; ++q) {
            float4 wa = wv[(4 * lane + j) * 4 + q];
            wreg[j][4 * q + 0] = wa.x; wreg[j][4 * q + 1] = wa.y;
            wreg[j][4 * q + 2] = wa.z; wreg[j][4 * q + 3] = wa.w;
            float4 wb = wv[(256 + 4 * lane + j) * 4 + q];
            wreg[4 + j][4 * q + 0] = wb.x; wreg[4 + j][4 * q + 1] = wb.y;
            wreg[4 + j][4 * q + 2] = wb.z; wreg[4 + j][4 * q + 3] = wb.w;
        }
    }

    int row = wid;
    float4 a = make_float4(0.f, 0.f, 0.f, 0.f), b = a;
    if (row < n) { a = xv[row * 128 + lane]; b = xv[row * 128 + 64 + lane]; }
    for (; row < n; row += nw) {
        int nrow = row + nw;
        float4 a2 = a, b2 = b;
        if (nrow < n) { a2 = xv[nrow * 128 + lane]; b2 = xv[nrow * 128 + 64 + lane]; }

        float av[8] = {a.x, a.y, a.z, a.w, b.x, b.y, b.z, b.w};
        float acc[16];
#pragma unroll
        for (int o = 0; o < 16; ++o) acc[o] = 0.f;
#pragma unroll
        for (int j = 0; j < 8; ++j)
#pragma unroll
            for (int o = 0; o < 16; ++o) acc[o] = fmaf(av[j], wreg[j][o], acc[o]);

#pragma unroll
        for (int i = 0; i < 8; ++i) {
            float send = (lane & 32) ? acc[i] : acc[i + 8];
            float recv = __shfl_xor(send, 32);
            float keep = (lane & 32) ? acc[i + 8] : acc[i];
            acc[i] = keep + recv;
        }
#pragma unroll
        for (int i = 0; i < 4; ++i) {
            float send = (lane & 16) ? acc[i] : acc[i + 4];
            float recv = __shfl_xor(send, 16);
            float keep = (lane & 16) ? acc[i + 4] : acc[i];
            acc[i] = keep + recv;
        }
#pragma unroll
        for (int i = 0; i < 2; ++i) {
            float send = (lane & 8) ? acc[i] : acc[i + 2];
            float recv = __shfl_xor(send, 8);
            float keep = (lane & 8) ? acc[i + 2] : acc[i];
            acc[i] = keep + recv;
        }
        {
            float send = (lane & 4) ? acc[0] : acc[1];
            float recv = __shfl_xor(send, 4);
            float keep = (lane & 4) ? acc[1] : acc[0];
            acc[0] = keep + recv;
        }
        float r = acc[0];
        r += __shfl_xor(r, 1);
        r += __shfl_xor(r, 2);
        if ((lane & 3) == 0) g1[(size_t)row * 16 + (lane >> 2)] = r * dinv[row];
        a = a2; b = b2;
    }
}

// Wave per node: gather-sum g1 over CSR neighbors (4-way MLP unroll), fuse
// h2=relu(...), h3=h2@W2, g2=h3*dinv.
// Lane layout: lane = eo*16 + f (4 edge slots x 16 features).
__global__ __launch_bounds__(256) void k_gather1(
    const int* __restrict__ row_start, const int* __restrict__ csr,
    const float* __restrict__ g1, const float* __restrict__ dinv,
    const float* __restrict__ W2, const float* __restrict__ b1,
    float* __restrict__ g2, int n) {
    const int wid = blockIdx.x * 4 + (threadIdx.x >> 6);
    if (wid >= n) return;
    const int lane = threadIdx.x & 63;
    const int f = lane & 15, eo = lane >> 4;
    const int base = row_start[wid];
    const int deg = row_start[wid + 1] - base;
    float acc = 0.f;
    int j = eo;
    // 4-way: 4 independent csr+gather chains in flight per lane.
    for (; j + 12 < deg; j += 16) {
        int s0 = csr[base + j];
        int s1 = csr[base + j + 4];
        int s2 = csr[base + j + 8];
        int s3 = csr[base + j + 12];
        float v0 = g1[(size_t)s0 * 16 + f];
        float v1 = g1[(size_t)s1 * 16 + f];
        float v2 = g1[(size_t)s2 * 16 + f];
        float v3 = g1[(size_t)s3 * 16 + f];
        acc += (v0 + v1) + (v2 + v3);
    }
    for (; j < deg; j += 4) {
        int s = csr[base + j];
        acc += g1[(size_t)s * 16 + f];
    }
    acc += __shfl_xor(acc, 16);
    acc += __shfl_xor(acc, 32);
    const float dv = dinv[wid];
    float h2 = fmaxf(fmaf(dv, acc + g1[(size_t)wid * 16 + f], b1[f]), 0.f);
    float p0 = h2 * W2[2 * f], p1 = h2 * W2[2 * f + 1];
#pragma unroll
    for (int m = 1; m < 16; m <<= 1) {
        p0 += __shfl_xor(p0, m);
        p1 += __shfl_xor(p1, m);
    }
    if (lane == 0) ((float2*)g2)[wid] = make_float2(p0 * dv, p1 * dv);
}

// Wave per node: gather-sum float2 g2 over CSR neighbors, fuse bias -> out.
__global__ __launch_bounds__(256) void k_gather2(
    const int* __restrict__ row_start, const int* __restrict__ csr,
    const float* __restrict__ g2, const float* __restrict__ dinv,
    const float* __restrict__ b2, float* __restrict__ out, int n) {
    const int wid = blockIdx.x * 4 + (threadIdx.x >> 6);
    if (wid >= n) return;
    const int lane = threadIdx.x & 63;
    const int base = row_start[wid];
    const int deg = row_start[wid + 1] - base;
    float a0 = 0.f, a1 = 0.f;
    for (int j = lane; j < deg; j += 64) {
        int s = csr[base + j];
        float2 v = ((const float2*)g2)[s];
        a0 += v.x; a1 += v.y;
    }
#pragma unroll
    for (int m = 1; m < 64; m <<= 1) {
        a0 += __shfl_xor(a0, m);
        a1 += __shfl_xor(a1, m);
    }
    if (lane == 0) {
        float dv = dinv[wid];
        float2 g = ((const float2*)g2)[wid];
        ((float2*)out)[wid] = make_float2(fmaf(dv, a0 + g.x, b2[0]),
                                          fmaf(dv, a1 + g.y, b2[1]));
    }
}

extern "C" void kernel_launch(void* const* d_in, const int* in_sizes, int n_in,
                              void* d_out, int out_size, void* d_ws, size_t ws_size,
                              hipStream_t stream) {
    const float* x  = (const float*)d_in[0];
    const int*   ei = (const int*)d_in[1];
    const float* W1 = (const float*)d_in[2];
    const float* b1 = (const float*)d_in[3];
    const float* W2 = (const float*)d_in[4];
    const float* b2 = (const float*)d_in[5];
    float* out = (float*)d_out;

    const int n = in_sizes[0] / 512;
    const int E = in_sizes[1] / 2;
    const int* src = ei;
    const int* dst = ei + E;

    const int NB = (n + (1 << BKT_SHIFT) - 1) >> BKT_SHIFT;      // buckets (<=512)
    const int nb_bin = (E + 256 * BIN_EPT - 1) / (256 * BIN_EPT); // bin blocks

    char* ws = (char*)d_ws;
    size_t off = 0;
    auto alloc = [&](size_t bytes) {
        char* p = ws + off;
        off += (bytes + 255) & ~(size_t)255;
        return p;
    };
    float* dinv      = (float*)alloc((size_t)n * 4);
    float* g1        = (float*)alloc((size_t)n * 16 * 4);
    float* g2        = (float*)alloc((size_t)n * 2 * 4);
    int*   row_start = (int*)alloc(((size_t)n + 1) * 4);  // +1 sentinel
    int*   csr       = (int*)alloc((size_t)E * 4);
    int*   binned    = (int*)alloc((size_t)E * 4);
    int*   bucket_cnt    = (int*)alloc((size_t)NB * 4);
    int*   bucket_base   = (int*)alloc((size_t)NB * 4);
    int*   bucket_cursor = (int*)alloc((size_t)NB * 4);

    hipMemsetAsync(bucket_cnt, 0, (size_t)NB * 4, stream);

    const int nb_w = (n + 3) / 4;    // wave-per-node kernels, 4 waves/block

    // k_bin dynamic LDS: h/ls/gb (3*NB ints) + sorted (4096 ints) + bkt (4096 u16)
    const int bin_lds = 3 * NB * 4 + 256 * BIN_EPT * 4 + 256 * BIN_EPT * 2;

    k_bhist<<<nb_bin, 256, NB * 4, stream>>>(dst, bucket_cnt, E, NB);
    k_scan_nb<<<1, 512, 0, stream>>>(bucket_cnt, bucket_base, bucket_cursor, NB);
    k_bin<<<nb_bin, 256, bin_lds, stream>>>(src, dst, bucket_cursor, binned, E, NB);
    k_place<<<NB, 512, 0, stream>>>(binned, bucket_base, row_start, dinv, csr, E, n, NB);
    k_gemm1<<<2048, 256, 0, stream>>>(x, W1, dinv, g1, n);
    k_gather1<<<nb_w, 256, 0, stream>>>(row_start, csr, g1, dinv, W2, b1, g2, n);
    k_gather2<<<nb_w, 256, 0, stream>>>(row_start, csr, g2, dinv, b2, out, n);
}

// Round 12
// 244.879 us; speedup vs baseline: 2.1541x; 1.0036x over previous
//
#include <hip/hip_runtime.h>

// GCN 2-layer forward, CSR-gather formulation. All fp32.
// out[d] = dinv[d] * ( sum_{e: src->d} g[src] + g[d] ) + bias,
// where g[i] = (h W)[i] * dinv[i]; self-loop is the +g[d] term.
// CSR built via binned partition (atomic-reserve + LDS counting sort):
//   k_bhist:  LDS bucket histogram -> global atomicAdd bucket totals
//   k_scan_nb: scan totals -> bucket_base; seed bucket_cursor = base
//   k_bin:    stage edges in regs, LDS hist+scan, one global reserve per
//             (block,bucket), LDS counting sort, COALESCED write of packed
//             (src<<8|dst&255) runs into bucket regions
//   k_place:  per-bucket (512 thr): per-node counts/scan in LDS, emit
//             row_start (sentinel row_start[n]=E) + dinv, place csr.
//   k_gemm1:  g1 = (x @ W1) * dinv  (wave-per-row, W resident in VGPRs via
//             __launch_bounds__(256,2) -- default heuristic capped at 88
//             VGPR and demoted the 128-float W fragment to per-row reloads)
//   k_gather1: CSR gather of g1 (4-way MLP unroll) + fused relu/W2 -> g2
//   k_gather2: CSR gather of g2 + bias -> out
// deg is implicit: row_start[i+1] - row_start[i].

#define BKT_SHIFT 8            // 256 nodes per bucket
#define BIN_EPT 16             // edges per thread in binning kernels (4096/block)

// LDS bucket histogram of dst -> global atomic bucket totals.
__global__ __launch_bounds__(256) void k_bhist(
    const int* __restrict__ dst, int* __restrict__ bucket_cnt, int E, int NB) {
    extern __shared__ int h[];  // NB ints
    const int t = threadIdx.x;
    const int base = blockIdx.x * (256 * BIN_EPT);
    for (int b = t; b < NB; b += 256) h[b] = 0;
    __syncthreads();
#pragma unroll
    for (int j = 0; j < BIN_EPT; ++j) {
        int e = base + j * 256 + t;
        if (e < E) atomicAdd(&h[dst[e] >> BKT_SHIFT], 1);
    }
    __syncthreads();
    for (int b = t; b < NB; b += 256) {
        int c = h[b];
        if (c > 0) atomicAdd(&bucket_cnt[b], c);
    }
}

// Exclusive scan of NB (<=512) bucket totals -> bucket_base; seed cursor.
__global__ __launch_bounds__(512) void k_scan_nb(
    const int* __restrict__ bucket_cnt, int* __restrict__ bucket_base,
    int* __restrict__ bucket_cursor, int NB) {
    __shared__ int lds[512];
    const int t = threadIdx.x;
    int v = (t < NB) ? bucket_cnt[t] : 0;
    lds[t] = v;
    __syncthreads();
    for (int off = 1; off < 512; off <<= 1) {
        int u = (t >= off) ? lds[t - off] : 0;
        __syncthreads();
        lds[t] += u;
        __syncthreads();
    }
    if (t < NB) {
        int base = lds[t] - v;
        bucket_base[t] = base;
        bucket_cursor[t] = base;
    }
}

// Bin packed edges (src<<8 | dst&255) into per-bucket regions of `binned`.
// LDS counting sort inside the block -> coalesced run writes.
// Dynamic LDS layout: h[NB] (hist->cursor), ls[NB] (local excl start),
// gb[NB] (global base), sorted[4096] int, bkt[4096] ushort.
__global__ __launch_bounds__(256) void k_bin(
    const int* __restrict__ src, const int* __restrict__ dst,
    int* __restrict__ bucket_cursor, int* __restrict__ binned, int E, int NB) {
    extern __shared__ int lds[];
    int* h  = lds;
    int* ls = lds + NB;
    int* gb = lds + 2 * NB;
    int* sorted = lds + 3 * NB;
    unsigned short* bkt = (unsigned short*)(sorted + 256 * BIN_EPT);
    const int t = threadIdx.x;
    const int base = blockIdx.x * (256 * BIN_EPT);
    const int count = min(256 * BIN_EPT, E - base);  // valid edges this block

    for (int b = t; b < NB; b += 256) h[b] = 0;
    __syncthreads();
    // Stage edges in registers + local histogram.
    int s_[BIN_EPT], d_[BIN_EPT];
#pragma unroll
    for (int j = 0; j < BIN_EPT; ++j) {
        int e = base + j * 256 + t;
        if (e < E) {
            s_[j] = src[e];
            d_[j] = dst[e];
            atomicAdd(&h[d_[j] >> BKT_SHIFT], 1);
        }
    }
    __syncthreads();
    // Inclusive Hillis-Steele scan of h into ls (512 padded slots, 2/thread).
    {
        int i0 = t, i1 = t + 256;
        ls[i0] = (i0 < NB) ? h[i0] : 0;
        ls[i1] = (i1 < NB) ? h[i1] : 0;
        __syncthreads();
        for (int off = 1; off < 512; off <<= 1) {
            int a0 = (i0 >= off) ? ls[i0 - off] : 0;
            int a1 = (i1 >= off) ? ls[i1 - off] : 0;
            __syncthreads();
            ls[i0] += a0; ls[i1] += a1;
            __syncthreads();
        }
    }
    // ls -> exclusive; reserve global space; h becomes local sort cursor.
    for (int b = t; b < NB; b += 256) {
        int c = h[b];
        int ex = ls[b] - c;
        ls[b] = ex;
        gb[b] = (c > 0) ? atomicAdd(&bucket_cursor[b], c) : 0;
        h[b] = ex;
    }
    __syncthreads();
    // Counting sort into LDS.
#pragma unroll
    for (int j = 0; j < BIN_EPT; ++j) {
        int e = base + j * 256 + t;
        if (e < E) {
            int b = d_[j] >> BKT_SHIFT;
            int r = atomicAdd(&h[b], 1);
            sorted[r] = (s_[j] << BKT_SHIFT) | (d_[j] & 255);
            bkt[r] = (unsigned short)b;
        }
    }
    __syncthreads();
    // Coalesced write-out: consecutive slots -> consecutive positions in the
    // same bucket's reserved region.
#pragma unroll
    for (int j = 0; j < BIN_EPT; ++j) {
        int i = j * 256 + t;
        if (i < count) {
            int b = bkt[i];
            binned[gb[b] + (i - ls[b])] = sorted[i];
        }
    }
}

// One block (512 thr) per bucket: per-node degree count in LDS (4x staged),
// LDS scan -> row_start (sentinel row_start[n]=E) + dinv, place csr.
__global__ __launch_bounds__(512) void k_place(
    const int* __restrict__ binned, const int* __restrict__ bucket_base,
    int* __restrict__ row_start, float* __restrict__ dinv,
    int* __restrict__ csr, int E, int n, int NB) {
    __shared__ int lcnt[256], sc[256];
    const int b = blockIdx.x;
    const int t = threadIdx.x;
    const int lo = bucket_base[b];
    const int hi = (b + 1 < NB) ? bucket_base[b + 1] : E;
    if (t < 256) lcnt[t] = 0;
    __syncthreads();
    int i = lo + t;
    for (; i + 3 * 512 < hi; i += 4 * 512) {
        int v0 = binned[i], v1 = binned[i + 512];
        int v2 = binned[i + 1024], v3 = binned[i + 1536];
        atomicAdd(&lcnt[v0 & 255], 1);
        atomicAdd(&lcnt[v1 & 255], 1);
        atomicAdd(&lcnt[v2 & 255], 1);
        atomicAdd(&lcnt[v3 & 255], 1);
    }
    for (; i < hi; i += 512) atomicAdd(&lcnt[binned[i] & 255], 1);
    __syncthreads();
    int c = 0;
    if (t < 256) { c = lcnt[t]; sc[t] = c; }
    __syncthreads();
    for (int off = 1; off < 256; off <<= 1) {
        int u = 0;
        if (t < 256 && t >= off) u = sc[t - off];
        __syncthreads();
        if (t < 256) sc[t] += u;
        __syncthreads();
    }
    if (t < 256) {
        int excl = sc[t] - c;
        const int node = (b << BKT_SHIFT) + t;
        if (node <= n) {
            row_start[node] = lo + excl;  // node==n -> hi==E sentinel
            if (node < n) dinv[node] = rsqrtf((float)c + 1.0f);
        }
        lcnt[t] = excl;  // becomes the local cursor
    }
    __syncthreads();
    i = lo + t;
    for (; i + 3 * 512 < hi; i += 4 * 512) {
        int v0 = binned[i], v1 = binned[i + 512];
        int v2 = binned[i + 1024], v3 = binned[i + 1536];
        int r0 = atomicAdd(&lcnt[v0 & 255], 1); csr[lo + r0] = v0 >> BKT_SHIFT;
        int r1 = atomicAdd(&lcnt[v1 & 255], 1); csr[lo + r1] = v1 >> BKT_SHIFT;
        int r2 = atomicAdd(&lcnt[v2 & 255], 1); csr[lo + r2] = v2 >> BKT_SHIFT;
        int r3 = atomicAdd(&lcnt[v3 & 255], 1); csr[lo + r3] = v3 >> BKT_SHIFT;
    }
    for (; i < hi; i += 512) {
        int v = binned[i];
        int r = atomicAdd(&lcnt[v & 255], 1);
        csr[lo + r] = v >> BKT_SHIFT;
    }
}

// g1[row][o] = (x[row] @ W1)[o] * dinv[row]
// wave-per-row: lane l covers k in {4l..4l+3} u {256+4l..256+4l+3},
// W fragment in registers, reduce-scatter via shfl_xor.
// __launch_bounds__(256, 2): allow up to ~256 VGPR so the 128-float wreg
// stays register-resident across the row loop (default heuristic chose 88
// VGPR and reloaded W every iteration -> 117 us; see round-11 counters).
__global__ __launch_bounds__(256, 2) void k_gemm1(
    const float* __restrict__ x, const float* __restrict__ W1,
    const float* __restrict__ dinv, float* __restrict__ g1, int n) {
    const int lane = threadIdx.x & 63;
    const int wid  = blockIdx.x * (blockDim.x >> 6) + (threadIdx.x >> 6);
    const int nw   = gridDim.x * (blockDim.x >> 6);
    const float4* __restrict__ xv = (const float4*)x;
    const float4* __restrict__ wv = (const float4*)W1;

    float wreg[8][16];
#pragma unroll
    for (int j = 0; j < 4; ++j) {
#pragma unroll
        for (int q = 0; q < 4; ++q) {
            float4 wa = wv[(4 * lane + j) * 4 + q];
            wreg[j][4 * q + 0] = wa.x; wreg[j][4 * q + 1] = wa.y;
            wreg[j][4 * q + 2] = wa.z; wreg[j][4 * q + 3] = wa.w;
            float4 wb = wv[(256 + 4 * lane + j) * 4 + q];
            wreg[4 + j][4 * q + 0] = wb.x; wreg[4 + j][4 * q + 1] = wb.y;
            wreg[4 + j][4 * q + 2] = wb.z; wreg[4 + j][4 * q + 3] = wb.w;
        }
    }

    int row = wid;
    float4 a = make_float4(0.f, 0.f, 0.f, 0.f), b = a;
    if (row < n) { a = xv[row * 128 + lane]; b = xv[row * 128 + 64 + lane]; }
    for (; row < n; row += nw) {
        int nrow = row + nw;
        float4 a2 = a, b2 = b;
        if (nrow < n) { a2 = xv[nrow * 128 + lane]; b2 = xv[nrow * 128 + 64 + lane]; }

        float av[8] = {a.x, a.y, a.z, a.w, b.x, b.y, b.z, b.w};
        float acc[16];
#pragma unroll
        for (int o = 0; o < 16; ++o) acc[o] = 0.f;
#pragma unroll
        for (int j = 0; j < 8; ++j)
#pragma unroll
            for (int o = 0; o < 16; ++o) acc[o] = fmaf(av[j], wreg[j][o], acc[o]);

#pragma unroll
        for (int i = 0; i < 8; ++i) {
            float send = (lane & 32) ? acc[i] : acc[i + 8];
            float recv = __shfl_xor(send, 32);
            float keep = (lane & 32) ? acc[i + 8] : acc[i];
            acc[i] = keep + recv;
        }
#pragma unroll
        for (int i = 0; i < 4; ++i) {
            float send = (lane & 16) ? acc[i] : acc[i + 4];
            float recv = __shfl_xor(send, 16);
            float keep = (lane & 16) ? acc[i + 4] : acc[i];
            acc[i] = keep + recv;
        }
#pragma unroll
        for (int i = 0; i < 2; ++i) {
            float send = (lane & 8) ? acc[i] : acc[i + 2];
            float recv = __shfl_xor(send, 8);
            float keep = (lane & 8) ? acc[i + 2] : acc[i];
            acc[i] = keep + recv;
        }
        {
            float send = (lane & 4) ? acc[0] : acc[1];
            float recv = __shfl_xor(send, 4);
            float keep = (lane & 4) ? acc[1] : acc[0];
            acc[0] = keep + recv;
        }
        float r = acc[0];
        r += __shfl_xor(r, 1);
        r += __shfl_xor(r, 2);
        if ((lane & 3) == 0) g1[(size_t)row * 16 + (lane >> 2)] = r * dinv[row];
        a = a2; b = b2;
    }
}

// Wave per node: gather-sum g1 over CSR neighbors (4-way MLP unroll), fuse
// h2=relu(...), h3=h2@W2, g2=h3*dinv.
// Lane layout: lane = eo*16 + f (4 edge slots x 16 features).
__global__ __launch_bounds__(256) void k_gather1(
    const int* __restrict__ row_start, const int* __restrict__ csr,
    const float* __restrict__ g1, const float* __restrict__ dinv,
    const float* __restrict__ W2, const float* __restrict__ b1,
    float* __restrict__ g2, int n) {
    const int wid = blockIdx.x * 4 + (threadIdx.x >> 6);
    if (wid >= n) return;
    const int lane = threadIdx.x & 63;
    const int f = lane & 15, eo = lane >> 4;
    const int base = row_start[wid];
    const int deg = row_start[wid + 1] - base;
    float acc = 0.f;
    int j = eo;
    // 4-way: 4 independent csr+gather chains in flight per lane.
    for (; j + 12 < deg; j += 16) {
        int s0 = csr[base + j];
        int s1 = csr[base + j + 4];
        int s2 = csr[base + j + 8];
        int s3 = csr[base + j + 12];
        float v0 = g1[(size_t)s0 * 16 + f];
        float v1 = g1[(size_t)s1 * 16 + f];
        float v2 = g1[(size_t)s2 * 16 + f];
        float v3 = g1[(size_t)s3 * 16 + f];
        acc += (v0 + v1) + (v2 + v3);
    }
    for (; j < deg; j += 4) {
        int s = csr[base + j];
        acc += g1[(size_t)s * 16 + f];
    }
    acc += __shfl_xor(acc, 16);
    acc += __shfl_xor(acc, 32);
    const float dv = dinv[wid];
    float h2 = fmaxf(fmaf(dv, acc + g1[(size_t)wid * 16 + f], b1[f]), 0.f);
    float p0 = h2 * W2[2 * f], p1 = h2 * W2[2 * f + 1];
#pragma unroll
    for (int m = 1; m < 16; m <<= 1) {
        p0 += __shfl_xor(p0, m);
        p1 += __shfl_xor(p1, m);
    }
    if (lane == 0) ((float2*)g2)[wid] = make_float2(p0 * dv, p1 * dv);
}

// Wave per node: gather-sum float2 g2 over CSR neighbors, fuse bias -> out.
__global__ __launch_bounds__(256) void k_gather2(
    const int* __restrict__ row_start, const int* __restrict__ csr,
    const float* __restrict__ g2, const float* __restrict__ dinv,
    const float* __restrict__ b2, float* __restrict__ out, int n) {
    const int wid = blockIdx.x * 4 + (threadIdx.x >> 6);
    if (wid >= n) return;
    const int lane = threadIdx.x & 63;
    const int base = row_start[wid];
    const int deg = row_start[wid + 1] - base;
    float a0 = 0.f, a1 = 0.f;
    for (int j = lane; j < deg; j += 64) {
        int s = csr[base + j];
        float2 v = ((const float2*)g2)[s];
        a0 += v.x; a1 += v.y;
    }
#pragma unroll
    for (int m = 1; m < 64; m <<= 1) {
        a0 += __shfl_xor(a0, m);
        a1 += __shfl_xor(a1, m);
    }
    if (lane == 0) {
        float dv = dinv[wid];
        float2 g = ((const float2*)g2)[wid];
        ((float2*)out)[wid] = make_float2(fmaf(dv, a0 + g.x, b2[0]),
                                          fmaf(dv, a1 + g.y, b2[1]));
    }
}

extern "C" void kernel_launch(void* const* d_in, const int* in_sizes, int n_in,
                              void* d_out, int out_size, void* d_ws, size_t ws_size,
                              hipStream_t stream) {
    const float* x  = (const float*)d_in[0];
    const int*   ei = (const int*)d_in[1];
    const float* W1 = (const float*)d_in[2];
    const float* b1 = (const float*)d_in[3];
    const float* W2 = (const float*)d_in[4];
    const float* b2 = (const float*)d_in[5];
    float* out = (float*)d_out;

    const int n = in_sizes[0] / 512;
    const int E = in_sizes[1] / 2;
    const int* src = ei;
    const int* dst = ei + E;

    const int NB = (n + (1 << BKT_SHIFT) - 1) >> BKT_SHIFT;      // buckets (<=512)
    const int nb_bin = (E + 256 * BIN_EPT - 1) / (256 * BIN_EPT); // bin blocks

    char* ws = (char*)d_ws;
    size_t off = 0;
    auto alloc = [&](size_t bytes) {
        char* p = ws + off;
        off += (bytes + 255) & ~(size_t)255;
        return p;
    };
    float* dinv      = (float*)alloc((size_t)n * 4);
    float* g1        = (float*)alloc((size_t)n * 16 * 4);
    float* g2        = (float*)alloc((size_t)n * 2 * 4);
    int*   row_start = (int*)alloc(((size_t)n + 1) * 4);  // +1 sentinel
    int*   csr       = (int*)alloc((size_t)E * 4);
    int*   binned    = (int*)alloc((size_t)E * 4);
    int*   bucket_cnt    = (int*)alloc((size_t)NB * 4);
    int*   bucket_base   = (int*)alloc((size_t)NB * 4);
    int*   bucket_cursor = (int*)alloc((size_t)NB * 4);

    hipMemsetAsync(bucket_cnt, 0, (size_t)NB * 4, stream);

    const int nb_w = (n + 3) / 4;    // wave-per-node kernels, 4 waves/block

    // k_bin dynamic LDS: h/ls/gb (3*NB ints) + sorted (4096 ints) + bkt (4096 u16)
    const int bin_lds = 3 * NB * 4 + 256 * BIN_EPT * 4 + 256 * BIN_EPT * 2;

    k_bhist<<<nb_bin, 256, NB * 4, stream>>>(dst, bucket_cnt, E, NB);
    k_scan_nb<<<1, 512, 0, stream>>>(bucket_cnt, bucket_base, bucket_cursor, NB);
    k_bin<<<nb_bin, 256, bin_lds, stream>>>(src, dst, bucket_cursor, binned, E, NB);
    k_place<<<NB, 512, 0, stream>>>(binned, bucket_base, row_start, dinv, csr, E, n, NB);
    k_gemm1<<<2048, 256, 0, stream>>>(x, W1, dinv, g1, n);
    k_gather1<<<nb_w, 256, 0, stream>>>(row_start, csr, g1, dinv, W2, b1, g2, n);
    k_gather2<<<nb_w, 256, 0, stream>>>(row_start, csr, g2, dinv, b2, out, n);
}

// Round 13
// 220.227 us; speedup vs baseline: 2.3953x; 1.1119x over previous
//
#include <hip/hip_runtime.h>

// GCN 2-layer forward, CSR-gather formulation. All fp32.
// out[d] = dinv[d] * ( sum_{e: src->d} g[src] + g[d] ) + bias,
// where g[i] = (h W)[i] * dinv[i]; self-loop is the +g[d] term.
// CSR built via binned partition (atomic-reserve + LDS counting sort):
//   k_bhist:  LDS bucket histogram -> global atomicAdd bucket totals
//   k_scan_nb: scan totals -> bucket_base; seed bucket_cursor = base
//   k_bin:    stage edges in regs, LDS hist+scan, one global reserve per
//             (block,bucket), LDS counting sort, COALESCED write of packed
//             (src<<8|dst&255) runs into bucket regions
//   k_place:  per-bucket (512 thr): per-node counts/scan in LDS, emit
//             row_start (sentinel row_start[n]=E) + dinv, place csr.
//   k_gemm1:  g1 = (x @ W1) * dinv. W1 staged in LDS (o-major, XOR-swizzled
//             -> conflict-free b128 reads); 4 rows per wave per iteration so
//             LDS traffic is 8KB/row and VALU/LDS are balanced. (Register-
//             resident W failed: compiler pins VGPR=88 and rematerializes
//             the W loads every row -> 116us of L1/L2 re-reads, r11/r12.)
//   k_gather1: CSR gather of g1 (4-way MLP unroll) + fused relu/W2 -> g2
//   k_gather2: CSR gather of g2 + bias -> out
// deg is implicit: row_start[i+1] - row_start[i].

#define BKT_SHIFT 8            // 256 nodes per bucket
#define BIN_EPT 16             // edges per thread in binning kernels (4096/block)

// LDS bucket histogram of dst -> global atomic bucket totals.
__global__ __launch_bounds__(256) void k_bhist(
    const int* __restrict__ dst, int* __restrict__ bucket_cnt, int E, int NB) {
    extern __shared__ int h[];  // NB ints
    const int t = threadIdx.x;
    const int base = blockIdx.x * (256 * BIN_EPT);
    for (int b = t; b < NB; b += 256) h[b] = 0;
    __syncthreads();
#pragma unroll
    for (int j = 0; j < BIN_EPT; ++j) {
        int e = base + j * 256 + t;
        if (e < E) atomicAdd(&h[dst[e] >> BKT_SHIFT], 1);
    }
    __syncthreads();
    for (int b = t; b < NB; b += 256) {
        int c = h[b];
        if (c > 0) atomicAdd(&bucket_cnt[b], c);
    }
}

// Exclusive scan of NB (<=512) bucket totals -> bucket_base; seed cursor.
__global__ __launch_bounds__(512) void k_scan_nb(
    const int* __restrict__ bucket_cnt, int* __restrict__ bucket_base,
    int* __restrict__ bucket_cursor, int NB) {
    __shared__ int lds[512];
    const int t = threadIdx.x;
    int v = (t < NB) ? bucket_cnt[t] : 0;
    lds[t] = v;
    __syncthreads();
    for (int off = 1; off < 512; off <<= 1) {
        int u = (t >= off) ? lds[t - off] : 0;
        __syncthreads();
        lds[t] += u;
        __syncthreads();
    }
    if (t < NB) {
        int base = lds[t] - v;
        bucket_base[t] = base;
        bucket_cursor[t] = base;
    }
}

// Bin packed edges (src<<8 | dst&255) into per-bucket regions of `binned`.
// LDS counting sort inside the block -> coalesced run writes.
// Dynamic LDS layout: h[NB] (hist->cursor), ls[NB] (local excl start),
// gb[NB] (global base), sorted[4096] int, bkt[4096] ushort.
__global__ __launch_bounds__(256) void k_bin(
    const int* __restrict__ src, const int* __restrict__ dst,
    int* __restrict__ bucket_cursor, int* __restrict__ binned, int E, int NB) {
    extern __shared__ int lds[];
    int* h  = lds;
    int* ls = lds + NB;
    int* gb = lds + 2 * NB;
    int* sorted = lds + 3 * NB;
    unsigned short* bkt = (unsigned short*)(sorted + 256 * BIN_EPT);
    const int t = threadIdx.x;
    const int base = blockIdx.x * (256 * BIN_EPT);
    const int count = min(256 * BIN_EPT, E - base);  // valid edges this block

    for (int b = t; b < NB; b += 256) h[b] = 0;
    __syncthreads();
    // Stage edges in registers + local histogram.
    int s_[BIN_EPT], d_[BIN_EPT];
#pragma unroll
    for (int j = 0; j < BIN_EPT; ++j) {
        int e = base + j * 256 + t;
        if (e < E) {
            s_[j] = src[e];
            d_[j] = dst[e];
            atomicAdd(&h[d_[j] >> BKT_SHIFT], 1);
        }
    }
    __syncthreads();
    // Inclusive Hillis-Steele scan of h into ls (512 padded slots, 2/thread).
    {
        int i0 = t, i1 = t + 256;
        ls[i0] = (i0 < NB) ? h[i0] : 0;
        ls[i1] = (i1 < NB) ? h[i1] : 0;
        __syncthreads();
        for (int off = 1; off < 512; off <<= 1) {
            int a0 = (i0 >= off) ? ls[i0 - off] : 0;
            int a1 = (i1 >= off) ? ls[i1 - off] : 0;
            __syncthreads();
            ls[i0] += a0; ls[i1] += a1;
            __syncthreads();
        }
    }
    // ls -> exclusive; reserve global space; h becomes local sort cursor.
    for (int b = t; b < NB; b += 256) {
        int c = h[b];
        int ex = ls[b] - c;
        ls[b] = ex;
        gb[b] = (c > 0) ? atomicAdd(&bucket_cursor[b], c) : 0;
        h[b] = ex;
    }
    __syncthreads();
    // Counting sort into LDS.
#pragma unroll
    for (int j = 0; j < BIN_EPT; ++j) {
        int e = base + j * 256 + t;
        if (e < E) {
            int b = d_[j] >> BKT_SHIFT;
            int r = atomicAdd(&h[b], 1);
            sorted[r] = (s_[j] << BKT_SHIFT) | (d_[j] & 255);
            bkt[r] = (unsigned short)b;
        }
    }
    __syncthreads();
    // Coalesced write-out: consecutive slots -> consecutive positions in the
    // same bucket's reserved region.
#pragma unroll
    for (int j = 0; j < BIN_EPT; ++j) {
        int i = j * 256 + t;
        if (i < count) {
            int b = bkt[i];
            binned[gb[b] + (i - ls[b])] = sorted[i];
        }
    }
}

// One block (512 thr) per bucket: per-node degree count in LDS (4x staged),
// LDS scan -> row_start (sentinel row_start[n]=E) + dinv, place csr.
__global__ __launch_bounds__(512) void k_place(
    const int* __restrict__ binned, const int* __restrict__ bucket_base,
    int* __restrict__ row_start, float* __restrict__ dinv,
    int* __restrict__ csr, int E, int n, int NB) {
    __shared__ int lcnt[256], sc[256];
    const int b = blockIdx.x;
    const int t = threadIdx.x;
    const int lo = bucket_base[b];
    const int hi = (b + 1 < NB) ? bucket_base[b + 1] : E;
    if (t < 256) lcnt[t] = 0;
    __syncthreads();
    int i = lo + t;
    for (; i + 3 * 512 < hi; i += 4 * 512) {
        int v0 = binned[i], v1 = binned[i + 512];
        int v2 = binned[i + 1024], v3 = binned[i + 1536];
        atomicAdd(&lcnt[v0 & 255], 1);
        atomicAdd(&lcnt[v1 & 255], 1);
        atomicAdd(&lcnt[v2 & 255], 1);
        atomicAdd(&lcnt[v3 & 255], 1);
    }
    for (; i < hi; i += 512) atomicAdd(&lcnt[binned[i] & 255], 1);
    __syncthreads();
    int c = 0;
    if (t < 256) { c = lcnt[t]; sc[t] = c; }
    __syncthreads();
    for (int off = 1; off < 256; off <<= 1) {
        int u = 0;
        if (t < 256 && t >= off) u = sc[t - off];
        __syncthreads();
        if (t < 256) sc[t] += u;
        __syncthreads();
    }
    if (t < 256) {
        int excl = sc[t] - c;
        const int node = (b << BKT_SHIFT) + t;
        if (node <= n) {
            row_start[node] = lo + excl;  // node==n -> hi==E sentinel
            if (node < n) dinv[node] = rsqrtf((float)c + 1.0f);
        }
        lcnt[t] = excl;  // becomes the local cursor
    }
    __syncthreads();
    i = lo + t;
    for (; i + 3 * 512 < hi; i += 4 * 512) {
        int v0 = binned[i], v1 = binned[i + 512];
        int v2 = binned[i + 1024], v3 = binned[i + 1536];
        int r0 = atomicAdd(&lcnt[v0 & 255], 1); csr[lo + r0] = v0 >> BKT_SHIFT;
        int r1 = atomicAdd(&lcnt[v1 & 255], 1); csr[lo + r1] = v1 >> BKT_SHIFT;
        int r2 = atomicAdd(&lcnt[v2 & 255], 1); csr[lo + r2] = v2 >> BKT_SHIFT;
        int r3 = atomicAdd(&lcnt[v3 & 255], 1); csr[lo + r3] = v3 >> BKT_SHIFT;
    }
    for (; i < hi; i += 512) {
        int v = binned[i];
        int r = atomicAdd(&lcnt[v & 255], 1);
        csr[lo + r] = v >> BKT_SHIFT;
    }
}

// g1[row][o] = (x[row] @ W1)[o] * dinv[row]
// W1 staged in LDS, o-major with XOR swizzle: element (k,o) lives at word
// o*512 + (k ^ ((o&7)<<2)). Read side: lane l's float4 for output o at
// words o*512 + 4*(l^(o&7)) (+256 for the second k-half) -- the canonical
// conflict-free 16B-stride pattern. 4 rows per wave per iteration: 32 LDS
// b128 reads amortized over 512 FMAs.
#define G1R 4
__global__ __launch_bounds__(256, 2) void k_gemm1(
    const float* __restrict__ x, const float* __restrict__ W1,
    const float* __restrict__ dinv, float* __restrict__ g1, int n) {
    __shared__ float wlds[16 * 512];
    const int t = threadIdx.x;
    for (int i = t; i < 8192; i += 256) {
        int k = i >> 4, o = i & 15;
        wlds[o * 512 + (k ^ ((o & 7) << 2))] = W1[i];
    }
    __syncthreads();

    const int lane = t & 63;
    const int wid  = blockIdx.x * 4 + (t >> 6);
    const int nw   = gridDim.x * 4;
    const float4* __restrict__ xv = (const float4*)x;

    for (int r0 = wid * G1R; r0 < n; r0 += nw * G1R) {
        float4 a[G1R], b[G1R];
#pragma unroll
        for (int r = 0; r < G1R; ++r) {
            a[r] = make_float4(0.f, 0.f, 0.f, 0.f);
            b[r] = a[r];
            if (r0 + r < n) {
                a[r] = xv[(size_t)(r0 + r) * 128 + lane];
                b[r] = xv[(size_t)(r0 + r) * 128 + 64 + lane];
            }
        }
        float acc[G1R][16];
#pragma unroll
        for (int r = 0; r < G1R; ++r)
#pragma unroll
            for (int o = 0; o < 16; ++o) acc[r][o] = 0.f;

#pragma unroll
        for (int o = 0; o < 16; ++o) {
            const int lp = lane ^ (o & 7);
            float4 wa = *(const float4*)&wlds[o * 512 + 4 * lp];
            float4 wb = *(const float4*)&wlds[o * 512 + 256 + 4 * lp];
#pragma unroll
            for (int r = 0; r < G1R; ++r) {
                float s = fmaf(a[r].x, wa.x, acc[r][o]);
                s = fmaf(a[r].y, wa.y, s);
                s = fmaf(a[r].z, wa.z, s);
                s = fmaf(a[r].w, wa.w, s);
                s = fmaf(b[r].x, wb.x, s);
                s = fmaf(b[r].y, wb.y, s);
                s = fmaf(b[r].z, wb.z, s);
                acc[r][o] = fmaf(b[r].w, wb.w, s);
            }
        }
        // NOTE: lane holds partials for k in {4*lp..4*lp+3, 256+...}, but the
        // reduce sums over ALL 64 lanes per output o, so the lane permutation
        // lp = lane^(o&7) is reduction-invariant.
#pragma unroll
        for (int r = 0; r < G1R; ++r) {
            if (r0 + r >= n) break;
            float red[16];
#pragma unroll
            for (int o = 0; o < 16; ++o) red[o] = acc[r][o];
#pragma unroll
            for (int i = 0; i < 8; ++i) {
                float send = (lane & 32) ? red[i] : red[i + 8];
                float recv = __shfl_xor(send, 32);
                float keep = (lane & 32) ? red[i + 8] : red[i];
                red[i] = keep + recv;
            }
#pragma unroll
            for (int i = 0; i < 4; ++i) {
                float send = (lane & 16) ? red[i] : red[i + 4];
                float recv = __shfl_xor(send, 16);
                float keep = (lane & 16) ? red[i + 4] : red[i];
                red[i] = keep + recv;
            }
#pragma unroll
            for (int i = 0; i < 2; ++i) {
                float send = (lane & 8) ? red[i] : red[i + 2];
                float recv = __shfl_xor(send, 8);
                float keep = (lane & 8) ? red[i + 2] : red[i];
                red[i] = keep + recv;
            }
            {
                float send = (lane & 4) ? red[0] : red[1];
                float recv = __shfl_xor(send, 4);
                float keep = (lane & 4) ? red[1] : red[0];
                red[0] = keep + recv;
            }
            float v = red[0];
            v += __shfl_xor(v, 1);
            v += __shfl_xor(v, 2);
            if ((lane & 3) == 0)
                g1[(size_t)(r0 + r) * 16 + (lane >> 2)] = v * dinv[r0 + r];
        }
    }
}

// Wave per node: gather-sum g1 over CSR neighbors (4-way MLP unroll), fuse
// h2=relu(...), h3=h2@W2, g2=h3*dinv.
// Lane layout: lane = eo*16 + f (4 edge slots x 16 features).
__global__ __launch_bounds__(256) void k_gather1(
    const int* __restrict__ row_start, const int* __restrict__ csr,
    const float* __restrict__ g1, const float* __restrict__ dinv,
    const float* __restrict__ W2, const float* __restrict__ b1,
    float* __restrict__ g2, int n) {
    const int wid = blockIdx.x * 4 + (threadIdx.x >> 6);
    if (wid >= n) return;
    const int lane = threadIdx.x & 63;
    const int f = lane & 15, eo = lane >> 4;
    const int base = row_start[wid];
    const int deg = row_start[wid + 1] - base;
    float acc = 0.f;
    int j = eo;
    // 4-way: 4 independent csr+gather chains in flight per lane.
    for (; j + 12 < deg; j += 16) {
        int s0 = csr[base + j];
        int s1 = csr[base + j + 4];
        int s2 = csr[base + j + 8];
        int s3 = csr[base + j + 12];
        float v0 = g1[(size_t)s0 * 16 + f];
        float v1 = g1[(size_t)s1 * 16 + f];
        float v2 = g1[(size_t)s2 * 16 + f];
        float v3 = g1[(size_t)s3 * 16 + f];
        acc += (v0 + v1) + (v2 + v3);
    }
    for (; j < deg; j += 4) {
        int s = csr[base + j];
        acc += g1[(size_t)s * 16 + f];
    }
    acc += __shfl_xor(acc, 16);
    acc += __shfl_xor(acc, 32);
    const float dv = dinv[wid];
    float h2 = fmaxf(fmaf(dv, acc + g1[(size_t)wid * 16 + f], b1[f]), 0.f);
    float p0 = h2 * W2[2 * f], p1 = h2 * W2[2 * f + 1];
#pragma unroll
    for (int m = 1; m < 16; m <<= 1) {
        p0 += __shfl_xor(p0, m);
        p1 += __shfl_xor(p1, m);
    }
    if (lane == 0) ((float2*)g2)[wid] = make_float2(p0 * dv, p1 * dv);
}

// Wave per node: gather-sum float2 g2 over CSR neighbors, fuse bias -> out.
__global__ __launch_bounds__(256) void k_gather2(
    const int* __restrict__ row_start, const int* __restrict__ csr,
    const float* __restrict__ g2, const float* __restrict__ dinv,
    const float* __restrict__ b2, float* __restrict__ out, int n) {
    const int wid = blockIdx.x * 4 + (threadIdx.x >> 6);
    if (wid >= n) return;
    const int lane = threadIdx.x & 63;
    const int base = row_start[wid];
    const int deg = row_start[wid + 1] - base;
    float a0 = 0.f, a1 = 0.f;
    for (int j = lane; j < deg; j += 64) {
        int s = csr[base + j];
        float2 v = ((const float2*)g2)[s];
        a0 += v.x; a1 += v.y;
    }
#pragma unroll
    for (int m = 1; m < 64; m <<= 1) {
        a0 += __shfl_xor(a0, m);
        a1 += __shfl_xor(a1, m);
    }
    if (lane == 0) {
        float dv = dinv[wid];
        float2 g = ((const float2*)g2)[wid];
        ((float2*)out)[wid] = make_float2(fmaf(dv, a0 + g.x, b2[0]),
                                          fmaf(dv, a1 + g.y, b2[1]));
    }
}

extern "C" void kernel_launch(void* const* d_in, const int* in_sizes, int n_in,
                              void* d_out, int out_size, void* d_ws, size_t ws_size,
                              hipStream_t stream) {
    const float* x  = (const float*)d_in[0];
    const int*   ei = (const int*)d_in[1];
    const float* W1 = (const float*)d_in[2];
    const float* b1 = (const float*)d_in[3];
    const float* W2 = (const float*)d_in[4];
    const float* b2 = (const float*)d_in[5];
    float* out = (float*)d_out;

    const int n = in_sizes[0] / 512;
    const int E = in_sizes[1] / 2;
    const int* src = ei;
    const int* dst = ei + E;

    const int NB = (n + (1 << BKT_SHIFT) - 1) >> BKT_SHIFT;      // buckets (<=512)
    const int nb_bin = (E + 256 * BIN_EPT - 1) / (256 * BIN_EPT); // bin blocks

    char* ws = (char*)d_ws;
    size_t off = 0;
    auto alloc = [&](size_t bytes) {
        char* p = ws + off;
        off += (bytes + 255) & ~(size_t)255;
        return p;
    };
    float* dinv      = (float*)alloc((size_t)n * 4);
    float* g1        = (float*)alloc((size_t)n * 16 * 4);
    float* g2        = (float*)alloc((size_t)n * 2 * 4);
    int*   row_start = (int*)alloc(((size_t)n + 1) * 4);  // +1 sentinel
    int*   csr       = (int*)alloc((size_t)E * 4);
    int*   binned    = (int*)alloc((size_t)E * 4);
    int*   bucket_cnt    = (int*)alloc((size_t)NB * 4);
    int*   bucket_base   = (int*)alloc((size_t)NB * 4);
    int*   bucket_cursor = (int*)alloc((size_t)NB * 4);

    hipMemsetAsync(bucket_cnt, 0, (size_t)NB * 4, stream);

    const int nb_w = (n + 3) / 4;    // wave-per-node kernels, 4 waves/block

    // k_bin dynamic LDS: h/ls/gb (3*NB ints) + sorted (4096 ints) + bkt (4096 u16)
    const int bin_lds = 3 * NB * 4 + 256 * BIN_EPT * 4 + 256 * BIN_EPT * 2;

    k_bhist<<<nb_bin, 256, NB * 4, stream>>>(dst, bucket_cnt, E, NB);
    k_scan_nb<<<1, 512, 0, stream>>>(bucket_cnt, bucket_base, bucket_cursor, NB);
    k_bin<<<nb_bin, 256, bin_lds, stream>>>(src, dst, bucket_cursor, binned, E, NB);
    k_place<<<NB, 512, 0, stream>>>(binned, bucket_base, row_start, dinv, csr, E, n, NB);
    k_gemm1<<<1024, 256, 0, stream>>>(x, W1, dinv, g1, n);
    k_gather1<<<nb_w, 256, 0, stream>>>(row_start, csr, g1, dinv, W2, b1, g2, n);
    k_gather2<<<nb_w, 256, 0, stream>>>(row_start, csr, g2, dinv, b2, out, n);
}